// Round 2
// baseline (12622.613 us; speedup 1.0000x reference)
//
#include <hip/hip_runtime.h>
#include <stdint.h>
#include <math.h>

// ---------------------------------------------------------------------------
// p_net forward on MI355X.  B=4096 boards, N=81 cells, D=128, H=4 heads.
// Round 1: fp32 implementation + JAX *partitionable* Threefry stream
//   (jax_threefry_partitionable=True is the modern default: fold-like split,
//    random_bits elem i = o0^o1 of threefry(key, (0, i))).
// Outputs (concat, float32): pos[4096], num[4096], asc[4096*81*81].
// ---------------------------------------------------------------------------

#define NB 4096

__device__ __forceinline__ float silu_f(float v) {
  return v / (1.0f + expf(-v));
}

// ---------------- Threefry-2x32 (JAX-compatible) ---------------------------
__device__ __forceinline__ void tf_round(uint32_t& x0, uint32_t& x1, int r) {
  x0 += x1;
  x1 = (x1 << r) | (x1 >> (32 - r));
  x1 ^= x0;
}

__device__ __forceinline__ void threefry2x32(uint32_t k0, uint32_t k1,
                                             uint32_t x0, uint32_t x1,
                                             uint32_t& o0, uint32_t& o1) {
  uint32_t k2 = k0 ^ k1 ^ 0x1BD11BDAu;
  x0 += k0; x1 += k1;
  tf_round(x0,x1,13); tf_round(x0,x1,15); tf_round(x0,x1,26); tf_round(x0,x1,6);
  x0 += k1; x1 += k2 + 1u;
  tf_round(x0,x1,17); tf_round(x0,x1,29); tf_round(x0,x1,16); tf_round(x0,x1,24);
  x0 += k2; x1 += k0 + 2u;
  tf_round(x0,x1,13); tf_round(x0,x1,15); tf_round(x0,x1,26); tf_round(x0,x1,6);
  x0 += k0; x1 += k1 + 3u;
  tf_round(x0,x1,17); tf_round(x0,x1,29); tf_round(x0,x1,16); tf_round(x0,x1,24);
  x0 += k1; x1 += k2 + 4u;
  tf_round(x0,x1,13); tf_round(x0,x1,15); tf_round(x0,x1,26); tf_round(x0,x1,6);
  x0 += k2; x1 += k0 + 5u;
  o0 = x0; o1 = x1;
}

// Partitionable (fold-like) split of jax.random.key(42):
//   derived key j = threefry2x32(key, (0, j)) full output pair.
__device__ __forceinline__ void jax_split42(uint32_t& k1a, uint32_t& k1b,
                                            uint32_t& k2a, uint32_t& k2b) {
  threefry2x32(0u, 42u, 0u, 0u, k1a, k1b);   // split row 0
  threefry2x32(0u, 42u, 0u, 1u, k2a, k2b);   // split row 1
}

// Partitionable random_bits(key, 32, shape): elem i (flat) = o0 ^ o1 of
// threefry2x32(key, (hi32(i), lo32(i))) ; our sizes < 2^32 so hi = 0.
__device__ __forceinline__ uint32_t jax_randbits(uint32_t ka, uint32_t kb,
                                                 uint32_t i) {
  uint32_t o0, o1;
  threefry2x32(ka, kb, 0u, i, o0, o1);
  return o0 ^ o1;
}

// jax gumbel: -log(-log(uniform(tiny, 1)))
__device__ __forceinline__ float jax_gumbel_bits(uint32_t bits) {
  float f = __uint_as_float((bits >> 9) | 0x3f800000u) - 1.0f;
  const float tiny = 1.17549435e-38f;
  float u = fmaxf(tiny, f + tiny);
  return -logf(-logf(u));
}

// ---------------- prep: conv1+conv2 table, conv3 weight repack -------------
// T2e[(d*11+g)*128 + oc] = sum_ic c2_w[oc,ic,d/3,d%3] * (c1_w[ic,g] + c1_b[ic]) ; g==10 -> 0
// w3r[(d*128+oc)*128+ic] = c3_w[oc,ic,d/3,d%3]
__global__ __launch_bounds__(256) void k_prep(
    const float* __restrict__ c1_w, const float* __restrict__ c1_b,
    const float* __restrict__ c2_w, const float* __restrict__ c3_w,
    float* __restrict__ T2e, float* __restrict__ w3r)
{
  int idx = blockIdx.x * 256 + threadIdx.x;
  if (idx < 9*11*128) {
    int oc = idx & 127;
    int t  = idx >> 7;
    int g  = t % 11;
    int d  = t / 11;
    float acc = 0.f;
    if (g < 10) {
      int di = d / 3, dj = d % 3;
      for (int ic = 0; ic < 64; ++ic) {
        float x1 = c1_w[ic*10 + g] + c1_b[ic];
        acc += c2_w[((oc*64 + ic)*3 + di)*3 + dj] * x1;
      }
    }
    T2e[idx] = acc;
  } else if (idx < 9*11*128 + 9*128*128) {
    int j  = idx - 9*11*128;
    int ic = j & 127;
    int t  = j >> 7;
    int oc = t & 127;
    int d  = t >> 7;
    w3r[j] = c3_w[(oc*128 + ic)*9 + d];
  }
}

// ---------------- stem: digits -> conv2(table) -> conv3 -> +emb ------------
__global__ __launch_bounds__(256) void k_stem(
    const float* __restrict__ s, const float* __restrict__ T2e,
    const float* __restrict__ c2_b, const float* __restrict__ w3r,
    const float* __restrict__ c3_b, const float* __restrict__ emb,
    float* __restrict__ xout, int* __restrict__ digits)
{
  __shared__ float x2s[121*128];   // padded 11x11 grid of 128-ch, zero border
  __shared__ int   dg[121];        // padded digit grid, 10 = sentinel (zero row)
  const int b   = blockIdx.x;
  const int tid = threadIdx.x;

  for (int i = tid; i < (121*128)/4; i += 256)
    ((float4*)x2s)[i] = make_float4(0.f, 0.f, 0.f, 0.f);
  if (tid < 121) dg[tid] = 10;
  __syncthreads();

  if (tid < 81) {
    const float* sp = s + (size_t)b*810 + tid;
    float dv = 0.f;
    #pragma unroll
    for (int c = 1; c < 10; ++c) dv += (float)c * sp[c*81];
    int d = (int)(dv + 0.5f);
    dg[(tid/9 + 1)*11 + (tid%9 + 1)] = d;
    digits[b*81 + tid] = d;
  }
  __syncthreads();

  const int oc4 = (tid & 31) * 4;   // 4 output channels per thread
  const int cg  = tid >> 5;         // 8 cell-groups of up to 11 cells

  // conv2 via table + silu -> x2s (padded layout, [cell_pad][128])
  {
    const float4 bias = *(const float4*)(c2_b + oc4);
    for (int ci = 0; ci < 11; ++ci) {
      int c  = cg*11 + ci;
      int rc = (c < 81) ? c : 0;
      int i = rc/9, j = rc%9;
      float4 a = bias;
      #pragma unroll
      for (int d = 0; d < 9; ++d) {
        int g = dg[(i + d/3)*11 + (j + d%3)];
        const float4 t = *(const float4*)(T2e + (d*11 + g)*128 + oc4);
        a.x += t.x; a.y += t.y; a.z += t.z; a.w += t.w;
      }
      a.x = silu_f(a.x); a.y = silu_f(a.y); a.z = silu_f(a.z); a.w = silu_f(a.w);
      if (c < 81)
        *(float4*)(x2s + ((i+1)*11 + (j+1))*128 + oc4) = a;
    }
  }
  __syncthreads();

  // conv3 + bias + silu + emb -> xout[b][cell][128]
  {
    float acc[11][4];
    #pragma unroll
    for (int ci = 0; ci < 11; ++ci) {
      acc[ci][0] = 0.f; acc[ci][1] = 0.f; acc[ci][2] = 0.f; acc[ci][3] = 0.f;
    }
    int pb[11];
    #pragma unroll
    for (int ci = 0; ci < 11; ++ci) {
      int c  = cg*11 + ci;
      int rc = (c < 81) ? c : 0;
      pb[ci] = (rc/9)*11 + (rc%9);
    }
    for (int d = 0; d < 9; ++d) {
      const int off = (d/3)*11 + (d%3);
      const float* wbase = w3r + (size_t)(d*128 + oc4)*128;
      for (int k = 0; k < 128; k += 4) {
        const float4 w0 = *(const float4*)(wbase + k);
        const float4 w1 = *(const float4*)(wbase + 128 + k);
        const float4 w2 = *(const float4*)(wbase + 256 + k);
        const float4 w3 = *(const float4*)(wbase + 384 + k);
        #pragma unroll
        for (int ci = 0; ci < 11; ++ci) {
          const float4 xv = *(const float4*)(x2s + (pb[ci] + off)*128 + k);
          acc[ci][0] += w0.x*xv.x + w0.y*xv.y + w0.z*xv.z + w0.w*xv.w;
          acc[ci][1] += w1.x*xv.x + w1.y*xv.y + w1.z*xv.z + w1.w*xv.w;
          acc[ci][2] += w2.x*xv.x + w2.y*xv.y + w2.z*xv.z + w2.w*xv.w;
          acc[ci][3] += w3.x*xv.x + w3.y*xv.y + w3.z*xv.z + w3.w*xv.w;
        }
      }
    }
    const float4 b3 = *(const float4*)(c3_b + oc4);
    #pragma unroll
    for (int ci = 0; ci < 11; ++ci) {
      int c = cg*11 + ci;
      if (c < 81) {
        const float4 e = *(const float4*)(emb + c*128 + oc4);
        float4 o;
        o.x = silu_f(acc[ci][0] + b3.x) + e.x;
        o.y = silu_f(acc[ci][1] + b3.y) + e.y;
        o.z = silu_f(acc[ci][2] + b3.z) + e.z;
        o.w = silu_f(acc[ci][3] + b3.w) + e.w;
        *(float4*)(xout + ((size_t)b*81 + c)*128 + oc4) = o;
      }
    }
  }
}

// ---------------- attention: per board, loop 4 heads -----------------------
__global__ __launch_bounds__(256) void k_attn(
    const float* __restrict__ x, const float* __restrict__ in_w,
    const float* __restrict__ in_b, float* __restrict__ ctx,
    float* __restrict__ asc)
{
  __shared__ float qkv[96*85];     // rows: q 0..31, k 32..63, v 64..95 ; [m][n]
  __shared__ float sc[81*85];      // scores then attention probs [q][k]
  __shared__ float rmax[81], rinv[81];
  const int b   = blockIdx.x;
  const int tid = threadIdx.x;
  const float* xb = x + (size_t)b*81*128;

  for (int h = 0; h < 4; ++h) {
    // ---- qkv: 192 threads, m = column (0..95), 2 cell-groups
    if (tid < 192) {
      const int m  = tid % 96;
      const int ng = tid / 96;
      const int r  = (m < 32) ? (h*32 + m)
                   : (m < 64) ? (128 + h*32 + (m - 32))
                              : (256 + h*32 + (m - 64));
      const float4* wr = (const float4*)(in_w + (size_t)r*128);
      const float bias = in_b[r];
      const int n0 = ng*41;
      float acc[41];
      #pragma unroll
      for (int i = 0; i < 41; ++i) acc[i] = 0.f;
      for (int k4 = 0; k4 < 32; ++k4) {
        const float4 w4 = wr[k4];
        #pragma unroll
        for (int ni = 0; ni < 41; ++ni) {
          int n = n0 + ni; n = (n < 81) ? n : 80;
          const float4 xv = *(const float4*)(xb + n*128 + k4*4);
          acc[ni] += w4.x*xv.x + w4.y*xv.y + w4.z*xv.z + w4.w*xv.w;
        }
      }
      #pragma unroll
      for (int ni = 0; ni < 41; ++ni) {
        int n = n0 + ni;
        if (n < 81) qkv[m*85 + n] = acc[ni] + bias;
      }
    }
    __syncthreads();

    // ---- scores + structural mask
    {
      const int ki = tid & 127;
      const int qg = tid >> 7;
      if (ki < 81) {
        const int q0 = qg*41;
        float acc[41];
        #pragma unroll
        for (int i = 0; i < 41; ++i) acc[i] = 0.f;
        for (int j = 0; j < 32; ++j) {
          const float kv = qkv[(32 + j)*85 + ki];
          #pragma unroll
          for (int qi = 0; qi < 41; ++qi) {
            int q = q0 + qi; q = (q < 81) ? q : 80;
            acc[qi] += qkv[j*85 + q] * kv;
          }
        }
        const int krow = ki/9, kcol = ki%9;
        const int kbox = (krow/3)*3 + (kcol/3);
        #pragma unroll
        for (int qi = 0; qi < 41; ++qi) {
          int q = q0 + qi;
          if (q < 81) {
            int qrow = q/9, qcol = q%9, qbox = (qrow/3)*3 + (qcol/3);
            float msk;
            if      (h == 0) msk = (qrow == krow) ? 1.f : 0.f;
            else if (h == 1) msk = (qcol == kcol) ? 1.f : 0.f;
            else if (h == 2) msk = (qbox == kbox) ? 1.f : 0.f;
            else             msk = 1.f;
            sc[q*85 + ki] = acc[qi] / 5.656854249492380195f + msk;
          }
        }
      }
    }
    __syncthreads();

    // ---- softmax stats per row
    if (tid < 81) {
      const float* row = sc + tid*85;
      float m = row[0];
      for (int k = 1; k < 81; ++k) m = fmaxf(m, row[k]);
      float sum = 0.f;
      for (int k = 0; k < 81; ++k) sum += expf(row[k] - m);
      rmax[tid] = m;
      rinv[tid] = 1.0f / sum;
    }
    __syncthreads();

    // ---- probs in place + asc accumulation (mean over heads)
    {
      float* ascb = asc + (size_t)b*6561;
      for (int idx = tid; idx < 6561; idx += 256) {
        int q = idx / 81;
        int k = idx - q*81;
        float a = expf(sc[q*85 + k] - rmax[q]) * rinv[q];
        sc[q*85 + k] = a;
        if (h == 0) ascb[idx] = 0.25f * a;
        else        ascb[idx] += 0.25f * a;
      }
    }
    __syncthreads();

    // ---- ctx = a @ v  -> ctx[b][n][h*32 + j]
    {
      const int j  = tid & 31;
      const int ng = tid >> 5;      // 8 groups of up to 11 cells
      const int n0 = ng*11;
      float acc[11];
      #pragma unroll
      for (int i = 0; i < 11; ++i) acc[i] = 0.f;
      for (int k = 0; k < 81; ++k) {
        const float vv = qkv[(64 + j)*85 + k];
        #pragma unroll
        for (int ci = 0; ci < 11; ++ci) {
          int n = n0 + ci; n = (n < 81) ? n : 80;
          acc[ci] += sc[n*85 + k] * vv;
        }
      }
      #pragma unroll
      for (int ci = 0; ci < 11; ++ci) {
        int n = n0 + ci;
        if (n < 81)
          ctx[((size_t)b*81 + n)*128 + h*32 + j] = acc[ci];
      }
    }
    __syncthreads();
  }
}

// ---------------- post: out-proj, LN, l1, l2, heads + sampling -------------
__global__ __launch_bounds__(256) void k_post(
    const float* __restrict__ ctx,
    const float* __restrict__ out_w, const float* __restrict__ out_b,
    const float* __restrict__ ln_g,  const float* __restrict__ ln_b,
    const float* __restrict__ l1_w,  const float* __restrict__ l1_b,
    const float* __restrict__ l2_w,  const float* __restrict__ l2_b,
    const float* __restrict__ pos_w, const float* __restrict__ pos_b,
    const float* __restrict__ num_w, const float* __restrict__ num_b,
    const int* __restrict__ digits,  float* __restrict__ dout)
{
  __shared__ float y[81*132];
  __shared__ float mu[81], rstd[81];
  __shared__ float vals[81];
  __shared__ int   posIdx;
  const int b   = blockIdx.x;
  const int tid = threadIdx.x;
  const int oc  = tid & 127;
  const int ng  = tid >> 7;
  const int n0  = ng*41;

  // ---- out projection
  {
    const float4* wr = (const float4*)(out_w + oc*128);
    const float* cb  = ctx + (size_t)b*81*128;
    float acc[41];
    #pragma unroll
    for (int i = 0; i < 41; ++i) acc[i] = 0.f;
    for (int k4 = 0; k4 < 32; ++k4) {
      const float4 w4 = wr[k4];
      #pragma unroll
      for (int ni = 0; ni < 41; ++ni) {
        int n = n0 + ni; n = (n < 81) ? n : 80;
        const float4 xv = *(const float4*)(cb + n*128 + k4*4);
        acc[ni] += w4.x*xv.x + w4.y*xv.y + w4.z*xv.z + w4.w*xv.w;
      }
    }
    const float bias = out_b[oc];
    #pragma unroll
    for (int ni = 0; ni < 41; ++ni) {
      int n = n0 + ni;
      if (n < 81) y[n*132 + oc] = acc[ni] + bias;
    }
  }
  __syncthreads();

  // ---- LayerNorm
  if (tid < 81) {
    const float* row = y + tid*132;
    float s = 0.f;
    for (int k = 0; k < 128; ++k) s += row[k];
    float m = s * (1.0f/128.0f);
    float v = 0.f;
    for (int k = 0; k < 128; ++k) { float d = row[k] - m; v += d*d; }
    v *= (1.0f/128.0f);
    mu[tid]   = m;
    rstd[tid] = 1.0f / sqrtf(v + 1e-5f);
  }
  __syncthreads();
  for (int idx = tid; idx < 81*128; idx += 256) {
    int n = idx >> 7, k = idx & 127;
    y[n*132 + k] = (y[n*132 + k] - mu[n]) * rstd[n] * ln_g[k] + ln_b[k];
  }
  __syncthreads();

  // ---- l1 (silu)
  {
    const float4* wr = (const float4*)(l1_w + oc*128);
    float acc[41];
    #pragma unroll
    for (int i = 0; i < 41; ++i) acc[i] = 0.f;
    for (int k4 = 0; k4 < 32; ++k4) {
      const float4 w4 = wr[k4];
      #pragma unroll
      for (int ni = 0; ni < 41; ++ni) {
        int n = n0 + ni; n = (n < 81) ? n : 80;
        const float4 xv = *(const float4*)(y + n*132 + k4*4);
        acc[ni] += w4.x*xv.x + w4.y*xv.y + w4.z*xv.z + w4.w*xv.w;
      }
    }
    const float bias = l1_b[oc];
    __syncthreads();   // all reads of y done before overwrite
    #pragma unroll
    for (int ni = 0; ni < 41; ++ni) {
      int n = n0 + ni;
      if (n < 81) y[n*132 + oc] = silu_f(acc[ni] + bias);
    }
  }
  __syncthreads();

  // ---- l2 (silu)
  {
    const float4* wr = (const float4*)(l2_w + oc*128);
    float acc[41];
    #pragma unroll
    for (int i = 0; i < 41; ++i) acc[i] = 0.f;
    for (int k4 = 0; k4 < 32; ++k4) {
      const float4 w4 = wr[k4];
      #pragma unroll
      for (int ni = 0; ni < 41; ++ni) {
        int n = n0 + ni; n = (n < 81) ? n : 80;
        const float4 xv = *(const float4*)(y + n*132 + k4*4);
        acc[ni] += w4.x*xv.x + w4.y*xv.y + w4.z*xv.z + w4.w*xv.w;
      }
    }
    const float bias = l2_b[oc];
    __syncthreads();
    #pragma unroll
    for (int ni = 0; ni < 41; ++ni) {
      int n = n0 + ni;
      if (n < 81) y[n*132 + oc] = silu_f(acc[ni] + bias);
    }
  }
  __syncthreads();

  // ---- position head + gumbel sampling
  uint32_t k1a, k1b, k2a, k2b;
  jax_split42(k1a, k1b, k2a, k2b);

  if (tid < 81) {
    const float* row = y + tid*132;
    float acc = 0.f;
    for (int k = 0; k < 128; ++k) acc += row[k] * pos_w[k];
    acc += pos_b[0];
    if (digits[b*81 + tid] != 0) acc = -1e9f;
    uint32_t bits = jax_randbits(k1a, k1b, (uint32_t)(b*81 + tid));
    vals[tid] = acc + jax_gumbel_bits(bits);
  }
  __syncthreads();
  if (tid == 0) {
    float best = vals[0]; int bi = 0;
    for (int n = 1; n < 81; ++n)
      if (vals[n] > best) { best = vals[n]; bi = n; }
    posIdx = bi;
    dout[b] = (float)bi;
  }
  __syncthreads();
  const int pos = posIdx;

  // ---- number head at sampled position
  if (tid < 10) {
    float acc = 0.f;
    const float* row = y + pos*132;
    const float* wr  = num_w + tid*128;
    for (int k = 0; k < 128; ++k) acc += row[k] * wr[k];
    acc += num_b[tid];
    if (tid == 0) acc = -INFINITY;
    uint32_t bits = jax_randbits(k2a, k2b, (uint32_t)(b*10 + tid));
    vals[tid] = acc + jax_gumbel_bits(bits);
  }
  __syncthreads();
  if (tid == 0) {
    float best = vals[0]; int bi = 0;
    for (int d = 1; d < 10; ++d)
      if (vals[d] > best) { best = vals[d]; bi = d; }
    dout[NB + b] = (float)bi;
  }
}

// ---------------------------------------------------------------------------
extern "C" void kernel_launch(void* const* d_in, const int* in_sizes, int n_in,
                              void* d_out, int out_size, void* d_ws, size_t ws_size,
                              hipStream_t stream) {
  const float* s     = (const float*)d_in[0];
  const float* c1_w  = (const float*)d_in[1];
  const float* c1_b  = (const float*)d_in[2];
  const float* c2_w  = (const float*)d_in[3];
  const float* c2_b  = (const float*)d_in[4];
  const float* c3_w  = (const float*)d_in[5];
  const float* c3_b  = (const float*)d_in[6];
  const float* emb   = (const float*)d_in[7];
  const float* in_w  = (const float*)d_in[8];
  const float* in_b  = (const float*)d_in[9];
  const float* out_w = (const float*)d_in[10];
  const float* out_b = (const float*)d_in[11];
  const float* ln_g  = (const float*)d_in[12];
  const float* ln_b  = (const float*)d_in[13];
  const float* l1_w  = (const float*)d_in[14];
  const float* l1_b  = (const float*)d_in[15];
  const float* l2_w  = (const float*)d_in[16];
  const float* l2_b  = (const float*)d_in[17];
  const float* pos_w = (const float*)d_in[18];
  const float* pos_b = (const float*)d_in[19];
  const float* num_w = (const float*)d_in[20];
  const float* num_b = (const float*)d_in[21];

  // workspace layout (floats): T2e | w3r | digits(int) | x | ctx
  float* ws     = (float*)d_ws;
  float* T2e    = ws;                         // 9*11*128     = 12672
  float* w3r    = ws + 12672;                 // 9*128*128    = 147456
  int*   digits = (int*)(ws + 160128);        // 4096*81      = 331776
  float* x      = ws + 160128 + 331776;       // 4096*81*128  = 42467328
  float* ctx    = x + 42467328;               // 4096*81*128  = 42467328

  float* dout = (float*)d_out;
  float* asc  = dout + 2*NB;                  // asc starts after pos, num

  k_prep<<<dim3((160128 + 255)/256), dim3(256), 0, stream>>>(
      c1_w, c1_b, c2_w, c3_w, T2e, w3r);
  k_stem<<<dim3(NB), dim3(256), 0, stream>>>(
      s, T2e, c2_b, w3r, c3_b, emb, x, digits);
  k_attn<<<dim3(NB), dim3(256), 0, stream>>>(
      x, in_w, in_b, ctx, asc);
  k_post<<<dim3(NB), dim3(256), 0, stream>>>(
      ctx, out_w, out_b, ln_g, ln_b, l1_w, l1_b, l2_w, l2_b,
      pos_w, pos_b, num_w, num_b, digits, dout);
}

// Round 3
// 9008.261 us; speedup vs baseline: 1.4012x; 1.4012x over previous
//
#include <hip/hip_runtime.h>
#include <stdint.h>
#include <math.h>

// ---------------------------------------------------------------------------
// p_net forward on MI355X.  B=4096 boards, N=81 cells, D=128, H=4 heads.
// Round 3: restructured k_attn (512 thr, dynamic LDS, register-tiled float4
// GEMM phases, asc in registers -> single write) and k_post (k-major LDS,
// transposed weights, 4oc x 12cell tiles). PRNG/sampling unchanged (passing).
// Outputs (concat, float32): pos[4096], num[4096], asc[4096*81*81].
// ---------------------------------------------------------------------------

#define NB 4096

__device__ __forceinline__ float silu_f(float v) {
  return v / (1.0f + expf(-v));
}

__device__ __forceinline__ float hsum4(const float4 v) {
  return (v.x + v.y) + (v.z + v.w);
}
__device__ __forceinline__ void fma4(float4& a, const float4 w, const float4 x) {
  a.x = fmaf(w.x, x.x, a.x); a.y = fmaf(w.y, x.y, a.y);
  a.z = fmaf(w.z, x.z, a.z); a.w = fmaf(w.w, x.w, a.w);
}
__device__ __forceinline__ void fma4b(float4& a, const float s, const float4 x) {
  a.x = fmaf(s, x.x, a.x); a.y = fmaf(s, x.y, a.y);
  a.z = fmaf(s, x.z, a.z); a.w = fmaf(s, x.w, a.w);
}
__device__ __forceinline__ float4 zero4() { return make_float4(0.f,0.f,0.f,0.f); }

// ---------------- Threefry-2x32 (JAX partitionable) ------------------------
__device__ __forceinline__ void tf_round(uint32_t& x0, uint32_t& x1, int r) {
  x0 += x1;
  x1 = (x1 << r) | (x1 >> (32 - r));
  x1 ^= x0;
}

__device__ __forceinline__ void threefry2x32(uint32_t k0, uint32_t k1,
                                             uint32_t x0, uint32_t x1,
                                             uint32_t& o0, uint32_t& o1) {
  uint32_t k2 = k0 ^ k1 ^ 0x1BD11BDAu;
  x0 += k0; x1 += k1;
  tf_round(x0,x1,13); tf_round(x0,x1,15); tf_round(x0,x1,26); tf_round(x0,x1,6);
  x0 += k1; x1 += k2 + 1u;
  tf_round(x0,x1,17); tf_round(x0,x1,29); tf_round(x0,x1,16); tf_round(x0,x1,24);
  x0 += k2; x1 += k0 + 2u;
  tf_round(x0,x1,13); tf_round(x0,x1,15); tf_round(x0,x1,26); tf_round(x0,x1,6);
  x0 += k0; x1 += k1 + 3u;
  tf_round(x0,x1,17); tf_round(x0,x1,29); tf_round(x0,x1,16); tf_round(x0,x1,24);
  x0 += k1; x1 += k2 + 4u;
  tf_round(x0,x1,13); tf_round(x0,x1,15); tf_round(x0,x1,26); tf_round(x0,x1,6);
  x0 += k2; x1 += k0 + 5u;
  o0 = x0; o1 = x1;
}

__device__ __forceinline__ void jax_split42(uint32_t& k1a, uint32_t& k1b,
                                            uint32_t& k2a, uint32_t& k2b) {
  threefry2x32(0u, 42u, 0u, 0u, k1a, k1b);
  threefry2x32(0u, 42u, 0u, 1u, k2a, k2b);
}

__device__ __forceinline__ uint32_t jax_randbits(uint32_t ka, uint32_t kb,
                                                 uint32_t i) {
  uint32_t o0, o1;
  threefry2x32(ka, kb, 0u, i, o0, o1);
  return o0 ^ o1;
}

__device__ __forceinline__ float jax_gumbel_bits(uint32_t bits) {
  float f = __uint_as_float((bits >> 9) | 0x3f800000u) - 1.0f;
  const float tiny = 1.17549435e-38f;
  float u = fmaxf(tiny, f + tiny);
  return -logf(-logf(u));
}

// ---------------- prep: conv tables + weight transposes --------------------
__global__ __launch_bounds__(256) void k_prep(
    const float* __restrict__ c1_w, const float* __restrict__ c1_b,
    const float* __restrict__ c2_w, const float* __restrict__ c3_w,
    const float* __restrict__ out_w, const float* __restrict__ l1_w,
    const float* __restrict__ l2_w,
    float* __restrict__ T2e, float* __restrict__ w3r,
    float* __restrict__ owT, float* __restrict__ l1T, float* __restrict__ l2T)
{
  int idx = blockIdx.x * 256 + threadIdx.x;
  if (idx < 9*11*128) {
    int oc = idx & 127;
    int t  = idx >> 7;
    int g  = t % 11;
    int d  = t / 11;
    float acc = 0.f;
    if (g < 10) {
      int di = d / 3, dj = d % 3;
      for (int ic = 0; ic < 64; ++ic) {
        float x1 = c1_w[ic*10 + g] + c1_b[ic];
        acc += c2_w[((oc*64 + ic)*3 + di)*3 + dj] * x1;
      }
    }
    T2e[idx] = acc;
  } else if (idx < 160128) {
    int j  = idx - 12672;
    int ic = j & 127;
    int t  = j >> 7;
    int oc = t & 127;
    int d  = t >> 7;
    w3r[j] = c3_w[(oc*128 + ic)*9 + d];
  } else if (idx < 176512) {
    int j = idx - 160128;                      // j = k*128 + oc
    owT[j] = out_w[(j & 127)*128 + (j >> 7)];
  } else if (idx < 192896) {
    int j = idx - 176512;
    l1T[j] = l1_w[(j & 127)*128 + (j >> 7)];
  } else if (idx < 209280) {
    int j = idx - 192896;
    l2T[j] = l2_w[(j & 127)*128 + (j >> 7)];
  }
}

// ---------------- stem: digits -> conv2(table) -> conv3 -> +emb ------------
// (unchanged from round 2 — known good; revisit after profiling)
__global__ __launch_bounds__(256) void k_stem(
    const float* __restrict__ s, const float* __restrict__ T2e,
    const float* __restrict__ c2_b, const float* __restrict__ w3r,
    const float* __restrict__ c3_b, const float* __restrict__ emb,
    float* __restrict__ xout, int* __restrict__ digits)
{
  __shared__ float x2s[121*128];
  __shared__ int   dg[121];
  const int b   = blockIdx.x;
  const int tid = threadIdx.x;

  for (int i = tid; i < (121*128)/4; i += 256)
    ((float4*)x2s)[i] = make_float4(0.f, 0.f, 0.f, 0.f);
  if (tid < 121) dg[tid] = 10;
  __syncthreads();

  if (tid < 81) {
    const float* sp = s + (size_t)b*810 + tid;
    float dv = 0.f;
    #pragma unroll
    for (int c = 1; c < 10; ++c) dv += (float)c * sp[c*81];
    int d = (int)(dv + 0.5f);
    dg[(tid/9 + 1)*11 + (tid%9 + 1)] = d;
    digits[b*81 + tid] = d;
  }
  __syncthreads();

  const int oc4 = (tid & 31) * 4;
  const int cg  = tid >> 5;

  {
    const float4 bias = *(const float4*)(c2_b + oc4);
    for (int ci = 0; ci < 11; ++ci) {
      int c  = cg*11 + ci;
      int rc = (c < 81) ? c : 0;
      int i = rc/9, j = rc%9;
      float4 a = bias;
      #pragma unroll
      for (int d = 0; d < 9; ++d) {
        int g = dg[(i + d/3)*11 + (j + d%3)];
        const float4 t = *(const float4*)(T2e + (d*11 + g)*128 + oc4);
        a.x += t.x; a.y += t.y; a.z += t.z; a.w += t.w;
      }
      a.x = silu_f(a.x); a.y = silu_f(a.y); a.z = silu_f(a.z); a.w = silu_f(a.w);
      if (c < 81)
        *(float4*)(x2s + ((i+1)*11 + (j+1))*128 + oc4) = a;
    }
  }
  __syncthreads();

  {
    float acc[11][4];
    #pragma unroll
    for (int ci = 0; ci < 11; ++ci) {
      acc[ci][0] = 0.f; acc[ci][1] = 0.f; acc[ci][2] = 0.f; acc[ci][3] = 0.f;
    }
    int pb[11];
    #pragma unroll
    for (int ci = 0; ci < 11; ++ci) {
      int c  = cg*11 + ci;
      int rc = (c < 81) ? c : 0;
      pb[ci] = (rc/9)*11 + (rc%9);
    }
    for (int d = 0; d < 9; ++d) {
      const int off = (d/3)*11 + (d%3);
      const float* wbase = w3r + (size_t)(d*128 + oc4)*128;
      for (int k = 0; k < 128; k += 4) {
        const float4 w0 = *(const float4*)(wbase + k);
        const float4 w1 = *(const float4*)(wbase + 128 + k);
        const float4 w2 = *(const float4*)(wbase + 256 + k);
        const float4 w3 = *(const float4*)(wbase + 384 + k);
        #pragma unroll
        for (int ci = 0; ci < 11; ++ci) {
          const float4 xv = *(const float4*)(x2s + (pb[ci] + off)*128 + k);
          acc[ci][0] += w0.x*xv.x + w0.y*xv.y + w0.z*xv.z + w0.w*xv.w;
          acc[ci][1] += w1.x*xv.x + w1.y*xv.y + w1.z*xv.z + w1.w*xv.w;
          acc[ci][2] += w2.x*xv.x + w2.y*xv.y + w2.z*xv.z + w2.w*xv.w;
          acc[ci][3] += w3.x*xv.x + w3.y*xv.y + w3.z*xv.z + w3.w*xv.w;
        }
      }
    }
    const float4 b3 = *(const float4*)(c3_b + oc4);
    #pragma unroll
    for (int ci = 0; ci < 11; ++ci) {
      int c = cg*11 + ci;
      if (c < 81) {
        const float4 e = *(const float4*)(emb + c*128 + oc4);
        float4 o;
        o.x = silu_f(acc[ci][0] + b3.x) + e.x;
        o.y = silu_f(acc[ci][1] + b3.y) + e.y;
        o.z = silu_f(acc[ci][2] + b3.z) + e.z;
        o.w = silu_f(acc[ci][3] + b3.w) + e.w;
        *(float4*)(xout + ((size_t)b*81 + c)*128 + oc4) = o;
      }
    }
  }
}

// ---------------- attention (rewritten) ------------------------------------
// 512 threads / board. Dynamic LDS layout (floats):
//  xL   @ 0      [81][132]  staged board activations (row-major, k-contig)
//  qkT  @ 10692  [84][68]   q,k cell-major: qkT[cell][m], m 0..31 q, 32..63 k
//  vL   @ 16404  [32][84]   v row-major: vL[j][cell]
//  sc   @ 19092  [81][84]   scores -> probs (pad cols zeroed)
//  red  @ 25896  [486]      softmax partials
//  rmax @ 26544  [81]
//  rinv @ 26625  [81]
// alloc 27392 floats (pads OOB-safe garbage reads from masked lanes)
#define ATTN_LDS_BYTES (27392*4)

__global__ __launch_bounds__(512) void k_attn(
    const float* __restrict__ x, const float* __restrict__ in_w,
    const float* __restrict__ in_b, float* __restrict__ ctxg,
    float* __restrict__ asc)
{
  extern __shared__ float sm[];
  float* xL   = sm;
  float* qkT  = sm + 10692;
  float* vL   = sm + 16404;
  float* sc   = sm + 19092;
  float* red  = sm + 25896;
  float* rmax = sm + 26544;
  float* rinv = sm + 26625;

  const int b   = blockIdx.x;
  const int tid = threadIdx.x;
  const int rg  = tid >> 5;     // 0..15
  const int cg  = tid & 31;     // 0..31

  // stage x -> xL (coalesced global float4)
  {
    const float4* xg = (const float4*)(x + (size_t)b*81*128);
    for (int i = tid; i < 81*32; i += 512) {
      int n = i >> 5, k4 = i & 31;
      *(float4*)(xL + n*132 + k4*4) = xg[n*32 + k4];
    }
  }

  float ascR[13];
  #pragma unroll
  for (int i = 0; i < 13; ++i) ascR[i] = 0.f;

  __syncthreads();

  for (int h = 0; h < 4; ++h) {
    // ---- QKV: rows m = rg*6+i (0..95), cells n = cg + {0,32,64}
    {
      float4 acc[6][3];
      #pragma unroll
      for (int i = 0; i < 6; ++i)
        { acc[i][0] = zero4(); acc[i][1] = zero4(); acc[i][2] = zero4(); }
      int rows[6];
      #pragma unroll
      for (int i = 0; i < 6; ++i) {
        int m = rg*6 + i;
        rows[i] = (m < 32) ? (h*32 + m)
                : (m < 64) ? (128 + h*32 + (m - 32))
                           : (256 + h*32 + (m - 64));
      }
      const float* x0p = xL + cg*132;
      const float* x1p = xL + (cg+32)*132;
      const float* x2p = xL + (cg+64)*132;
      for (int k4 = 0; k4 < 32; ++k4) {
        const int ko = k4*4;
        float4 x0 = *(const float4*)(x0p + ko);
        float4 x1 = *(const float4*)(x1p + ko);
        float4 x2 = *(const float4*)(x2p + ko);
        #pragma unroll
        for (int i = 0; i < 6; ++i) {
          float4 w = *(const float4*)(in_w + rows[i]*128 + ko);
          fma4(acc[i][0], w, x0);
          fma4(acc[i][1], w, x1);
          fma4(acc[i][2], w, x2);
        }
      }
      #pragma unroll
      for (int i = 0; i < 6; ++i) {
        const int m = rg*6 + i;
        const float bias = in_b[rows[i]];
        float s0 = hsum4(acc[i][0]) + bias;
        float s1 = hsum4(acc[i][1]) + bias;
        float s2 = hsum4(acc[i][2]) + bias;
        if (m < 64) {
          qkT[cg*68 + m]      = s0;
          qkT[(cg+32)*68 + m] = s1;
          if (cg+64 < 81) qkT[(cg+64)*68 + m] = s2;
        } else {
          const int j = m - 64;
          vL[j*84 + cg]      = s0;
          vL[j*84 + cg+32]   = s1;
          if (cg+64 < 81)      vL[j*84 + cg+64] = s2;
          else if (cg+64 < 84) vL[j*84 + cg+64] = 0.f;   // zero pad cols
        }
      }
    }
    __syncthreads();

    // ---- scores: q = rg*6+i, k = cg*3+j, dot over m=32 (float4 over m)
    {
      float4 acc[6][3];
      #pragma unroll
      for (int i = 0; i < 6; ++i)
        { acc[i][0] = zero4(); acc[i][1] = zero4(); acc[i][2] = zero4(); }
      const int q0 = rg*6, kc0 = cg*3;
      for (int m4 = 0; m4 < 8; ++m4) {
        const int mo = m4*4;
        float4 kv0 = *(const float4*)(qkT + (kc0+0)*68 + 32 + mo);
        float4 kv1 = *(const float4*)(qkT + (kc0+1)*68 + 32 + mo);
        float4 kv2 = *(const float4*)(qkT + (kc0+2)*68 + 32 + mo);
        #pragma unroll
        for (int i = 0; i < 6; ++i) {
          float4 qv = *(const float4*)(qkT + (q0+i)*68 + mo);
          fma4(acc[i][0], qv, kv0);
          fma4(acc[i][1], qv, kv1);
          fma4(acc[i][2], qv, kv2);
        }
      }
      #pragma unroll
      for (int i = 0; i < 6; ++i) {
        const int q = q0 + i;
        if (q < 81) {
          const int qrow = q/9, qcol = q - qrow*9;
          const int qbox = (qrow/3)*3 + qcol/3;
          #pragma unroll
          for (int jj = 0; jj < 3; ++jj) {
            const int k = kc0 + jj;
            if (k < 81) {
              const int krow = k/9, kcol = k - krow*9;
              const int kbox = (krow/3)*3 + kcol/3;
              float msk = (h==0) ? (qrow==krow ? 1.f : 0.f)
                        : (h==1) ? (qcol==kcol ? 1.f : 0.f)
                        : (h==2) ? (qbox==kbox ? 1.f : 0.f)
                                 : 1.f;
              sc[q*84 + k] = hsum4(acc[i][jj]) / 5.656854249492381f + msk;
            }
          }
        }
      }
    }
    __syncthreads();

    // ---- softmax: 6 threads per row
    if (tid < 486) {
      const int r = tid / 6, j = tid - (tid/6)*6;
      const int kb = j*14;
      float m = -INFINITY;
      for (int c = 0; c < 14; ++c) {
        int k = kb + c;
        if (k < 81) m = fmaxf(m, sc[r*84 + k]);
      }
      red[tid] = m;
    }
    __syncthreads();
    if (tid < 81) {
      float m = red[tid*6];
      #pragma unroll
      for (int j = 1; j < 6; ++j) m = fmaxf(m, red[tid*6 + j]);
      rmax[tid] = m;
    }
    __syncthreads();
    if (tid < 486) {
      const int r = tid / 6, j = tid - (tid/6)*6;
      const int kb = j*14;
      const float m = rmax[r];
      float ssum = 0.f;
      for (int c = 0; c < 14; ++c) {
        int k = kb + c;
        if (k < 81) ssum += expf(sc[r*84 + k] - m);
      }
      red[tid] = ssum;
    }
    __syncthreads();
    if (tid < 81) {
      float ssum = 0.f;
      #pragma unroll
      for (int j = 0; j < 6; ++j) ssum += red[tid*6 + j];
      rinv[tid] = 1.0f / ssum;
      sc[tid*84 + 81] = 0.f; sc[tid*84 + 82] = 0.f; sc[tid*84 + 83] = 0.f;
    }
    __syncthreads();

    // ---- probs in place + asc register accumulation
    #pragma unroll
    for (int i = 0; i < 13; ++i) {
      const int idx = tid + i*512;
      if (idx < 6561) {
        const int q = idx / 81, k = idx - q*81;
        float a = expf(sc[q*84 + k] - rmax[q]) * rinv[q];
        sc[q*84 + k] = a;
        ascR[i] += a;
      }
    }
    __syncthreads();

    // ---- ctx: n = (tid&31)*3+{0,1,2}, j = (tid>>5)*2+{0,1}; dot over k
    {
      const int ng = tid & 31, jg = tid >> 5;
      const int nb = ng*3, jb = jg*2;
      float4 a00=zero4(), a01=zero4(), a10=zero4(),
             a11=zero4(), a20=zero4(), a21=zero4();
      const float* v0p = vL + jb*84;
      const float* v1p = vL + (jb+1)*84;
      const float* p0p = sc + nb*84;
      const float* p1p = sc + (nb+1)*84;
      const float* p2p = sc + (nb+2)*84;
      for (int k4 = 0; k4 < 21; ++k4) {
        const int ko = k4*4;
        float4 v0 = *(const float4*)(v0p + ko);
        float4 v1 = *(const float4*)(v1p + ko);
        float4 p0 = *(const float4*)(p0p + ko);
        float4 p1 = *(const float4*)(p1p + ko);
        float4 p2 = *(const float4*)(p2p + ko);
        fma4(a00, p0, v0); fma4(a01, p0, v1);
        fma4(a10, p1, v0); fma4(a11, p1, v1);
        fma4(a20, p2, v0); fma4(a21, p2, v1);
      }
      float* cb = ctxg + ((size_t)b*128 + h*32)*81;
      if (nb   < 81) { cb[jb*81 + nb]       = hsum4(a00);
                       cb[(jb+1)*81 + nb]   = hsum4(a01); }
      if (nb+1 < 81) { cb[jb*81 + nb+1]     = hsum4(a10);
                       cb[(jb+1)*81 + nb+1] = hsum4(a11); }
      if (nb+2 < 81) { cb[jb*81 + nb+2]     = hsum4(a20);
                       cb[(jb+1)*81 + nb+2] = hsum4(a21); }
    }
    __syncthreads();
  } // heads

  // asc = mean over heads, single coalesced write
  #pragma unroll
  for (int i = 0; i < 13; ++i) {
    const int idx = tid + i*512;
    if (idx < 6561) asc[(size_t)b*6561 + idx] = 0.25f * ascR[i];
  }
}

// ---------------- post: out-proj, LN, l1, l2, heads + sampling -------------
// 256 threads / board. yT[k][n] k-major in LDS (45 KB -> 3 blocks/CU).
// GEMM phases: thread = (ocg 0..31: 4 oc via wT float4) x (ng 0..6: 12 cells).
__global__ __launch_bounds__(256) void k_post(
    const float* __restrict__ ctxg,
    const float* __restrict__ owT,  const float* __restrict__ out_b,
    const float* __restrict__ ln_g, const float* __restrict__ ln_b,
    const float* __restrict__ l1T,  const float* __restrict__ l1_b,
    const float* __restrict__ l2T,  const float* __restrict__ l2_b,
    const float* __restrict__ pos_w, const float* __restrict__ pos_b,
    const float* __restrict__ num_w, const float* __restrict__ num_b,
    const int* __restrict__ digits,  float* __restrict__ dout)
{
  __shared__ float yT[128*84];
  __shared__ float red[243];
  __shared__ float mu[81], rstd[81];
  __shared__ float vals[81];
  __shared__ int   posIdx;
  const int b   = blockIdx.x;
  const int tid = threadIdx.x;
  const int ocg = tid >> 3;   // 0..31
  const int ng  = tid & 7;    // 0..7 (ng==7 idle in GEMMs)

  // stage ctx (global [b][128][81]) -> yT[k][n]; zero pad cols 81..83
  {
    const float* cb = ctxg + (size_t)b*128*81;
    for (int i = tid; i < 128*81; i += 256) {
      int k = i / 81, n = i - k*81;
      yT[k*84 + n] = cb[i];
    }
    for (int i = tid; i < 128*3; i += 256) {
      int k = i / 3, c = i - k*3;
      yT[k*84 + 81 + c] = 0.f;
    }
  }
  __syncthreads();

  // ---- out projection (reads yT as ctx, writes yT as y) ----
  {
    float4 acc[4][3];
    #pragma unroll
    for (int c = 0; c < 4; ++c)
      { acc[c][0]=zero4(); acc[c][1]=zero4(); acc[c][2]=zero4(); }
    if (ng < 7) {
      for (int k = 0; k < 128; ++k) {
        const float4 wv = *(const float4*)(owT + k*128 + ocg*4);
        const float* yr = yT + k*84 + ng*12;
        float4 x0 = *(const float4*)(yr);
        float4 x1 = *(const float4*)(yr + 4);
        float4 x2 = *(const float4*)(yr + 8);
        fma4b(acc[0][0], wv.x, x0); fma4b(acc[0][1], wv.x, x1); fma4b(acc[0][2], wv.x, x2);
        fma4b(acc[1][0], wv.y, x0); fma4b(acc[1][1], wv.y, x1); fma4b(acc[1][2], wv.y, x2);
        fma4b(acc[2][0], wv.z, x0); fma4b(acc[2][1], wv.z, x1); fma4b(acc[2][2], wv.z, x2);
        fma4b(acc[3][0], wv.w, x0); fma4b(acc[3][1], wv.w, x1); fma4b(acc[3][2], wv.w, x2);
      }
    }
    __syncthreads();
    if (ng < 7) {
      #pragma unroll
      for (int c = 0; c < 4; ++c) {
        const float bv = out_b[ocg*4 + c];
        #pragma unroll
        for (int t = 0; t < 3; ++t) {
          float4 o = acc[c][t];
          o.x += bv; o.y += bv; o.z += bv; o.w += bv;
          *(float4*)(yT + (ocg*4 + c)*84 + ng*12 + t*4) = o;
        }
      }
    }
  }
  __syncthreads();

  // ---- LayerNorm over k (columns n) ----
  if (tid < 243) {
    const int n = tid/3, j = tid - (tid/3)*3;
    float ssum = 0.f;
    for (int c = 0; c < 43; ++c) {
      int k = j*43 + c;
      if (k < 128) ssum += yT[k*84 + n];
    }
    red[tid] = ssum;
  }
  __syncthreads();
  if (tid < 81)
    mu[tid] = (red[tid*3] + red[tid*3+1] + red[tid*3+2]) * (1.0f/128.0f);
  __syncthreads();
  if (tid < 243) {
    const int n = tid/3, j = tid - (tid/3)*3;
    const float m = mu[n];
    float ssum = 0.f;
    for (int c = 0; c < 43; ++c) {
      int k = j*43 + c;
      if (k < 128) { float d = yT[k*84 + n] - m; ssum += d*d; }
    }
    red[tid] = ssum;
  }
  __syncthreads();
  if (tid < 81) {
    float v = (red[tid*3] + red[tid*3+1] + red[tid*3+2]) * (1.0f/128.0f);
    rstd[tid] = 1.0f / sqrtf(v + 1e-5f);
  }
  __syncthreads();
  for (int i = tid; i < 128*81; i += 256) {
    const int k = i / 81, n = i - k*81;
    yT[k*84 + n] = (yT[k*84 + n] - mu[n]) * rstd[n] * ln_g[k] + ln_b[k];
  }
  __syncthreads();

  // ---- l1 (silu) ----
  {
    float4 acc[4][3];
    #pragma unroll
    for (int c = 0; c < 4; ++c)
      { acc[c][0]=zero4(); acc[c][1]=zero4(); acc[c][2]=zero4(); }
    if (ng < 7) {
      for (int k = 0; k < 128; ++k) {
        const float4 wv = *(const float4*)(l1T + k*128 + ocg*4);
        const float* yr = yT + k*84 + ng*12;
        float4 x0 = *(const float4*)(yr);
        float4 x1 = *(const float4*)(yr + 4);
        float4 x2 = *(const float4*)(yr + 8);
        fma4b(acc[0][0], wv.x, x0); fma4b(acc[0][1], wv.x, x1); fma4b(acc[0][2], wv.x, x2);
        fma4b(acc[1][0], wv.y, x0); fma4b(acc[1][1], wv.y, x1); fma4b(acc[1][2], wv.y, x2);
        fma4b(acc[2][0], wv.z, x0); fma4b(acc[2][1], wv.z, x1); fma4b(acc[2][2], wv.z, x2);
        fma4b(acc[3][0], wv.w, x0); fma4b(acc[3][1], wv.w, x1); fma4b(acc[3][2], wv.w, x2);
      }
    }
    __syncthreads();
    if (ng < 7) {
      #pragma unroll
      for (int c = 0; c < 4; ++c) {
        const float bv = l1_b[ocg*4 + c];
        #pragma unroll
        for (int t = 0; t < 3; ++t) {
          float4 o = acc[c][t];
          o.x = silu_f(o.x + bv); o.y = silu_f(o.y + bv);
          o.z = silu_f(o.z + bv); o.w = silu_f(o.w + bv);
          *(float4*)(yT + (ocg*4 + c)*84 + ng*12 + t*4) = o;
        }
      }
    }
  }
  __syncthreads();

  // ---- l2 (silu) ----
  {
    float4 acc[4][3];
    #pragma unroll
    for (int c = 0; c < 4; ++c)
      { acc[c][0]=zero4(); acc[c][1]=zero4(); acc[c][2]=zero4(); }
    if (ng < 7) {
      for (int k = 0; k < 128; ++k) {
        const float4 wv = *(const float4*)(l2T + k*128 + ocg*4);
        const float* yr = yT + k*84 + ng*12;
        float4 x0 = *(const float4*)(yr);
        float4 x1 = *(const float4*)(yr + 4);
        float4 x2 = *(const float4*)(yr + 8);
        fma4b(acc[0][0], wv.x, x0); fma4b(acc[0][1], wv.x, x1); fma4b(acc[0][2], wv.x, x2);
        fma4b(acc[1][0], wv.y, x0); fma4b(acc[1][1], wv.y, x1); fma4b(acc[1][2], wv.y, x2);
        fma4b(acc[2][0], wv.z, x0); fma4b(acc[2][1], wv.z, x1); fma4b(acc[2][2], wv.z, x2);
        fma4b(acc[3][0], wv.w, x0); fma4b(acc[3][1], wv.w, x1); fma4b(acc[3][2], wv.w, x2);
      }
    }
    __syncthreads();
    if (ng < 7) {
      #pragma unroll
      for (int c = 0; c < 4; ++c) {
        const float bv = l2_b[ocg*4 + c];
        #pragma unroll
        for (int t = 0; t < 3; ++t) {
          float4 o = acc[c][t];
          o.x = silu_f(o.x + bv); o.y = silu_f(o.y + bv);
          o.z = silu_f(o.z + bv); o.w = silu_f(o.w + bv);
          *(float4*)(yT + (ocg*4 + c)*84 + ng*12 + t*4) = o;
        }
      }
    }
  }
  __syncthreads();

  // ---- position head + gumbel sampling ----
  uint32_t k1a, k1b, k2a, k2b;
  jax_split42(k1a, k1b, k2a, k2b);

  if (tid < 243) {
    const int n = tid/3, j = tid - (tid/3)*3;
    float ssum = 0.f;
    for (int c = 0; c < 43; ++c) {
      int k = j*43 + c;
      if (k < 128) ssum += yT[k*84 + n] * pos_w[k];
    }
    red[tid] = ssum;
  }
  __syncthreads();
  if (tid < 81) {
    float acc = red[tid*3] + red[tid*3+1] + red[tid*3+2] + pos_b[0];
    if (digits[b*81 + tid] != 0) acc = -1e9f;
    uint32_t bits = jax_randbits(k1a, k1b, (uint32_t)(b*81 + tid));
    vals[tid] = acc + jax_gumbel_bits(bits);
  }
  __syncthreads();
  if (tid == 0) {
    float best = vals[0]; int bi = 0;
    for (int n = 1; n < 81; ++n)
      if (vals[n] > best) { best = vals[n]; bi = n; }
    posIdx = bi;
    dout[b] = (float)bi;
  }
  __syncthreads();
  const int pos = posIdx;

  // ---- number head at sampled position ----
  if (tid < 80) {
    const int d = tid >> 3, j = tid & 7;
    float ssum = 0.f;
    #pragma unroll
    for (int c = 0; c < 16; ++c) {
      int k = j*16 + c;
      ssum += yT[k*84 + pos] * num_w[d*128 + k];
    }
    red[tid] = ssum;
  }
  __syncthreads();
  if (tid < 10) {
    float acc = num_b[tid];
    #pragma unroll
    for (int j = 0; j < 8; ++j) acc += red[tid*8 + j];
    if (tid == 0) acc = -INFINITY;
    uint32_t bits = jax_randbits(k2a, k2b, (uint32_t)(b*10 + tid));
    vals[tid] = acc + jax_gumbel_bits(bits);
  }
  __syncthreads();
  if (tid == 0) {
    float best = vals[0]; int bi = 0;
    for (int d = 1; d < 10; ++d)
      if (vals[d] > best) { best = vals[d]; bi = d; }
    dout[NB + b] = (float)bi;
  }
}

// ---------------------------------------------------------------------------
extern "C" void kernel_launch(void* const* d_in, const int* in_sizes, int n_in,
                              void* d_out, int out_size, void* d_ws, size_t ws_size,
                              hipStream_t stream) {
  const float* s     = (const float*)d_in[0];
  const float* c1_w  = (const float*)d_in[1];
  const float* c1_b  = (const float*)d_in[2];
  const float* c2_w  = (const float*)d_in[3];
  const float* c2_b  = (const float*)d_in[4];
  const float* c3_w  = (const float*)d_in[5];
  const float* c3_b  = (const float*)d_in[6];
  const float* emb   = (const float*)d_in[7];
  const float* in_w  = (const float*)d_in[8];
  const float* in_b  = (const float*)d_in[9];
  const float* out_w = (const float*)d_in[10];
  const float* out_b = (const float*)d_in[11];
  const float* ln_g  = (const float*)d_in[12];
  const float* ln_b  = (const float*)d_in[13];
  const float* l1_w  = (const float*)d_in[14];
  const float* l1_b  = (const float*)d_in[15];
  const float* l2_w  = (const float*)d_in[16];
  const float* l2_b  = (const float*)d_in[17];
  const float* pos_w = (const float*)d_in[18];
  const float* pos_b = (const float*)d_in[19];
  const float* num_w = (const float*)d_in[20];
  const float* num_b = (const float*)d_in[21];

  // ws layout (floats):
  // T2e 0 (12672) | w3r 12672 (147456) | owT 160128 (16384) |
  // l1T 176512 (16384) | l2T 192896 (16384) | digits 209280 (331776 int) |
  // x 541056 (42467328) | ctxg 43008384 (42467328)
  float* ws     = (float*)d_ws;
  float* T2e    = ws;
  float* w3r    = ws + 12672;
  float* owT    = ws + 160128;
  float* l1T    = ws + 176512;
  float* l2T    = ws + 192896;
  int*   digits = (int*)(ws + 209280);
  float* x      = ws + 541056;
  float* ctxg   = ws + 43008384;

  float* dout = (float*)d_out;
  float* asc  = dout + 2*NB;

  static bool attr_set = false;
  (void)attr_set;
  hipFuncSetAttribute((const void*)k_attn,
                      hipFuncAttributeMaxDynamicSharedMemorySize,
                      ATTN_LDS_BYTES);

  k_prep<<<dim3(818), dim3(256), 0, stream>>>(
      c1_w, c1_b, c2_w, c3_w, out_w, l1_w, l2_w,
      T2e, w3r, owT, l1T, l2T);
  k_stem<<<dim3(NB), dim3(256), 0, stream>>>(
      s, T2e, c2_b, w3r, c3_b, emb, x, digits);
  k_attn<<<dim3(NB), dim3(512), ATTN_LDS_BYTES, stream>>>(
      x, in_w, in_b, ctxg, asc);
  k_post<<<dim3(NB), dim3(256), 0, stream>>>(
      ctxg, owT, out_b, ln_g, ln_b, l1T, l1_b, l2T, l2_b,
      pos_w, pos_b, num_w, num_b, digits, dout);
}

// Round 4
// 7807.494 us; speedup vs baseline: 1.6167x; 1.1538x over previous
//
#include <hip/hip_runtime.h>
#include <stdint.h>
#include <math.h>

// ---------------------------------------------------------------------------
// p_net forward on MI355X.  B=4096 boards, N=81 cells, D=128, H=4 heads.
// Round 4: k_attn de-spilled — scalar fmaf-chain accumulators (18 VGPRs vs 72)
// in QKV/scores/ctx phases + __launch_bounds__(512,2) (VGPR cap 256).
// Round-3 counters showed 18 GB/dispatch HBM traffic = register spill scratch.
// Outputs (concat, float32): pos[4096], num[4096], asc[4096*81*81].
// ---------------------------------------------------------------------------

#define NB 4096

__device__ __forceinline__ float silu_f(float v) {
  return v / (1.0f + expf(-v));
}

__device__ __forceinline__ float4 zero4() { return make_float4(0.f,0.f,0.f,0.f); }

__device__ __forceinline__ void fma4b(float4& a, const float s, const float4 x) {
  a.x = fmaf(s, x.x, a.x); a.y = fmaf(s, x.y, a.y);
  a.z = fmaf(s, x.z, a.z); a.w = fmaf(s, x.w, a.w);
}

// sequential dot-accumulate: a += w·x, 4 fmaf, scalar accumulator
__device__ __forceinline__ void dacc(float& a, const float4 w, const float4 x) {
  a = fmaf(w.x, x.x, a); a = fmaf(w.y, x.y, a);
  a = fmaf(w.z, x.z, a); a = fmaf(w.w, x.w, a);
}

// ---------------- Threefry-2x32 (JAX partitionable) ------------------------
__device__ __forceinline__ void tf_round(uint32_t& x0, uint32_t& x1, int r) {
  x0 += x1;
  x1 = (x1 << r) | (x1 >> (32 - r));
  x1 ^= x0;
}

__device__ __forceinline__ void threefry2x32(uint32_t k0, uint32_t k1,
                                             uint32_t x0, uint32_t x1,
                                             uint32_t& o0, uint32_t& o1) {
  uint32_t k2 = k0 ^ k1 ^ 0x1BD11BDAu;
  x0 += k0; x1 += k1;
  tf_round(x0,x1,13); tf_round(x0,x1,15); tf_round(x0,x1,26); tf_round(x0,x1,6);
  x0 += k1; x1 += k2 + 1u;
  tf_round(x0,x1,17); tf_round(x0,x1,29); tf_round(x0,x1,16); tf_round(x0,x1,24);
  x0 += k2; x1 += k0 + 2u;
  tf_round(x0,x1,13); tf_round(x0,x1,15); tf_round(x0,x1,26); tf_round(x0,x1,6);
  x0 += k0; x1 += k1 + 3u;
  tf_round(x0,x1,17); tf_round(x0,x1,29); tf_round(x0,x1,16); tf_round(x0,x1,24);
  x0 += k1; x1 += k2 + 4u;
  tf_round(x0,x1,13); tf_round(x0,x1,15); tf_round(x0,x1,26); tf_round(x0,x1,6);
  x0 += k2; x1 += k0 + 5u;
  o0 = x0; o1 = x1;
}

__device__ __forceinline__ void jax_split42(uint32_t& k1a, uint32_t& k1b,
                                            uint32_t& k2a, uint32_t& k2b) {
  threefry2x32(0u, 42u, 0u, 0u, k1a, k1b);
  threefry2x32(0u, 42u, 0u, 1u, k2a, k2b);
}

__device__ __forceinline__ uint32_t jax_randbits(uint32_t ka, uint32_t kb,
                                                 uint32_t i) {
  uint32_t o0, o1;
  threefry2x32(ka, kb, 0u, i, o0, o1);
  return o0 ^ o1;
}

__device__ __forceinline__ float jax_gumbel_bits(uint32_t bits) {
  float f = __uint_as_float((bits >> 9) | 0x3f800000u) - 1.0f;
  const float tiny = 1.17549435e-38f;
  float u = fmaxf(tiny, f + tiny);
  return -logf(-logf(u));
}

// ---------------- prep: conv tables + weight transposes --------------------
__global__ __launch_bounds__(256) void k_prep(
    const float* __restrict__ c1_w, const float* __restrict__ c1_b,
    const float* __restrict__ c2_w, const float* __restrict__ c3_w,
    const float* __restrict__ out_w, const float* __restrict__ l1_w,
    const float* __restrict__ l2_w,
    float* __restrict__ T2e, float* __restrict__ w3r,
    float* __restrict__ owT, float* __restrict__ l1T, float* __restrict__ l2T)
{
  int idx = blockIdx.x * 256 + threadIdx.x;
  if (idx < 9*11*128) {
    int oc = idx & 127;
    int t  = idx >> 7;
    int g  = t % 11;
    int d  = t / 11;
    float acc = 0.f;
    if (g < 10) {
      int di = d / 3, dj = d % 3;
      for (int ic = 0; ic < 64; ++ic) {
        float x1 = c1_w[ic*10 + g] + c1_b[ic];
        acc += c2_w[((oc*64 + ic)*3 + di)*3 + dj] * x1;
      }
    }
    T2e[idx] = acc;
  } else if (idx < 160128) {
    int j  = idx - 12672;
    int ic = j & 127;
    int t  = j >> 7;
    int oc = t & 127;
    int d  = t >> 7;
    w3r[j] = c3_w[(oc*128 + ic)*9 + d];
  } else if (idx < 176512) {
    int j = idx - 160128;                      // j = k*128 + oc
    owT[j] = out_w[(j & 127)*128 + (j >> 7)];
  } else if (idx < 192896) {
    int j = idx - 176512;
    l1T[j] = l1_w[(j & 127)*128 + (j >> 7)];
  } else if (idx < 209280) {
    int j = idx - 192896;
    l2T[j] = l2_w[(j & 127)*128 + (j >> 7)];
  }
}

// ---------------- stem: digits -> conv2(table) -> conv3 -> +emb ------------
__global__ __launch_bounds__(256) void k_stem(
    const float* __restrict__ s, const float* __restrict__ T2e,
    const float* __restrict__ c2_b, const float* __restrict__ w3r,
    const float* __restrict__ c3_b, const float* __restrict__ emb,
    float* __restrict__ xout, int* __restrict__ digits)
{
  __shared__ float x2s[121*128];
  __shared__ int   dg[121];
  const int b   = blockIdx.x;
  const int tid = threadIdx.x;

  for (int i = tid; i < (121*128)/4; i += 256)
    ((float4*)x2s)[i] = make_float4(0.f, 0.f, 0.f, 0.f);
  if (tid < 121) dg[tid] = 10;
  __syncthreads();

  if (tid < 81) {
    const float* sp = s + (size_t)b*810 + tid;
    float dv = 0.f;
    #pragma unroll
    for (int c = 1; c < 10; ++c) dv += (float)c * sp[c*81];
    int d = (int)(dv + 0.5f);
    dg[(tid/9 + 1)*11 + (tid%9 + 1)] = d;
    digits[b*81 + tid] = d;
  }
  __syncthreads();

  const int oc4 = (tid & 31) * 4;
  const int cg  = tid >> 5;

  {
    const float4 bias = *(const float4*)(c2_b + oc4);
    for (int ci = 0; ci < 11; ++ci) {
      int c  = cg*11 + ci;
      int rc = (c < 81) ? c : 0;
      int i = rc/9, j = rc%9;
      float4 a = bias;
      #pragma unroll
      for (int d = 0; d < 9; ++d) {
        int g = dg[(i + d/3)*11 + (j + d%3)];
        const float4 t = *(const float4*)(T2e + (d*11 + g)*128 + oc4);
        a.x += t.x; a.y += t.y; a.z += t.z; a.w += t.w;
      }
      a.x = silu_f(a.x); a.y = silu_f(a.y); a.z = silu_f(a.z); a.w = silu_f(a.w);
      if (c < 81)
        *(float4*)(x2s + ((i+1)*11 + (j+1))*128 + oc4) = a;
    }
  }
  __syncthreads();

  {
    float acc[11][4];
    #pragma unroll
    for (int ci = 0; ci < 11; ++ci) {
      acc[ci][0] = 0.f; acc[ci][1] = 0.f; acc[ci][2] = 0.f; acc[ci][3] = 0.f;
    }
    int pb[11];
    #pragma unroll
    for (int ci = 0; ci < 11; ++ci) {
      int c  = cg*11 + ci;
      int rc = (c < 81) ? c : 0;
      pb[ci] = (rc/9)*11 + (rc%9);
    }
    for (int d = 0; d < 9; ++d) {
      const int off = (d/3)*11 + (d%3);
      const float* wbase = w3r + (size_t)(d*128 + oc4)*128;
      for (int k = 0; k < 128; k += 4) {
        const float4 w0 = *(const float4*)(wbase + k);
        const float4 w1 = *(const float4*)(wbase + 128 + k);
        const float4 w2 = *(const float4*)(wbase + 256 + k);
        const float4 w3 = *(const float4*)(wbase + 384 + k);
        #pragma unroll
        for (int ci = 0; ci < 11; ++ci) {
          const float4 xv = *(const float4*)(x2s + (pb[ci] + off)*128 + k);
          acc[ci][0] += w0.x*xv.x + w0.y*xv.y + w0.z*xv.z + w0.w*xv.w;
          acc[ci][1] += w1.x*xv.x + w1.y*xv.y + w1.z*xv.z + w1.w*xv.w;
          acc[ci][2] += w2.x*xv.x + w2.y*xv.y + w2.z*xv.z + w2.w*xv.w;
          acc[ci][3] += w3.x*xv.x + w3.y*xv.y + w3.z*xv.z + w3.w*xv.w;
        }
      }
    }
    const float4 b3 = *(const float4*)(c3_b + oc4);
    #pragma unroll
    for (int ci = 0; ci < 11; ++ci) {
      int c = cg*11 + ci;
      if (c < 81) {
        const float4 e = *(const float4*)(emb + c*128 + oc4);
        float4 o;
        o.x = silu_f(acc[ci][0] + b3.x) + e.x;
        o.y = silu_f(acc[ci][1] + b3.y) + e.y;
        o.z = silu_f(acc[ci][2] + b3.z) + e.z;
        o.w = silu_f(acc[ci][3] + b3.w) + e.w;
        *(float4*)(xout + ((size_t)b*81 + c)*128 + oc4) = o;
      }
    }
  }
}

// ---------------- attention ------------------------------------------------
// 512 threads / board. Dynamic LDS layout (floats):
//  xL   @ 0      [81][132]  staged board activations (row-major, k-contig)
//  qkT  @ 10692  [84][68]   q,k cell-major: qkT[cell][m], m 0..31 q, 32..63 k
//  vL   @ 16404  [32][84]   v row-major: vL[j][cell]
//  sc   @ 19092  [81][84]   scores -> probs (pad cols zeroed)
//  red  @ 25896  [486]      softmax partials
//  rmax @ 26544  [81]
//  rinv @ 26625  [81]
#define ATTN_LDS_BYTES (27392*4)

__global__ __launch_bounds__(512, 2) void k_attn(
    const float* __restrict__ x, const float* __restrict__ in_w,
    const float* __restrict__ in_b, float* __restrict__ ctxg,
    float* __restrict__ asc)
{
  extern __shared__ float sm[];
  float* xL   = sm;
  float* qkT  = sm + 10692;
  float* vL   = sm + 16404;
  float* sc   = sm + 19092;
  float* red  = sm + 25896;
  float* rmax = sm + 26544;
  float* rinv = sm + 26625;

  const int b   = blockIdx.x;
  const int tid = threadIdx.x;
  const int rg  = tid >> 5;     // 0..15
  const int cg  = tid & 31;     // 0..31

  // stage x -> xL (coalesced global float4)
  {
    const float4* xg = (const float4*)(x + (size_t)b*81*128);
    for (int i = tid; i < 81*32; i += 512) {
      int n = i >> 5, k4 = i & 31;
      *(float4*)(xL + n*132 + k4*4) = xg[n*32 + k4];
    }
  }

  float ascR[13];
  #pragma unroll
  for (int i = 0; i < 13; ++i) ascR[i] = 0.f;

  __syncthreads();

  for (int h = 0; h < 4; ++h) {
    // ---- QKV: rows m = rg*6+i (0..95), cells n = cg + {0,32,64}
    // scalar accumulators (18 VGPRs) — sequential fmaf chains, no spill
    {
      float acc[18];
      #pragma unroll
      for (int i = 0; i < 18; ++i) acc[i] = 0.f;
      int rows[6];
      #pragma unroll
      for (int i = 0; i < 6; ++i) {
        int m = rg*6 + i;
        rows[i] = (m < 32) ? (h*32 + m)
                : (m < 64) ? (128 + h*32 + (m - 32))
                           : (256 + h*32 + (m - 64));
      }
      const float* x0p = xL + cg*132;
      const float* x1p = xL + (cg+32)*132;
      const float* x2p = xL + (cg+64)*132;
      for (int k4 = 0; k4 < 32; ++k4) {
        const int ko = k4*4;
        float4 x0 = *(const float4*)(x0p + ko);
        float4 x1 = *(const float4*)(x1p + ko);
        float4 x2 = *(const float4*)(x2p + ko);
        #pragma unroll
        for (int i = 0; i < 6; ++i) {
          float4 w = *(const float4*)(in_w + rows[i]*128 + ko);
          dacc(acc[i*3 + 0], w, x0);
          dacc(acc[i*3 + 1], w, x1);
          dacc(acc[i*3 + 2], w, x2);
        }
      }
      #pragma unroll
      for (int i = 0; i < 6; ++i) {
        const int m = rg*6 + i;
        const float bias = in_b[rows[i]];
        float s0 = acc[i*3 + 0] + bias;
        float s1 = acc[i*3 + 1] + bias;
        float s2 = acc[i*3 + 2] + bias;
        if (m < 64) {
          qkT[cg*68 + m]      = s0;
          qkT[(cg+32)*68 + m] = s1;
          if (cg+64 < 81) qkT[(cg+64)*68 + m] = s2;
        } else {
          const int j = m - 64;
          vL[j*84 + cg]      = s0;
          vL[j*84 + cg+32]   = s1;
          if (cg+64 < 81)      vL[j*84 + cg+64] = s2;
          else if (cg+64 < 84) vL[j*84 + cg+64] = 0.f;   // zero pad cols
        }
      }
    }
    __syncthreads();

    // ---- scores: q = rg*6+i, k = cg*3+jj, dot over m=32
    {
      float acc[18];
      #pragma unroll
      for (int i = 0; i < 18; ++i) acc[i] = 0.f;
      const int q0 = rg*6, kc0 = cg*3;
      for (int m4 = 0; m4 < 8; ++m4) {
        const int mo = m4*4;
        float4 kv0 = *(const float4*)(qkT + (kc0+0)*68 + 32 + mo);
        float4 kv1 = *(const float4*)(qkT + (kc0+1)*68 + 32 + mo);
        float4 kv2 = *(const float4*)(qkT + (kc0+2)*68 + 32 + mo);
        #pragma unroll
        for (int i = 0; i < 6; ++i) {
          float4 qv = *(const float4*)(qkT + (q0+i)*68 + mo);
          dacc(acc[i*3 + 0], qv, kv0);
          dacc(acc[i*3 + 1], qv, kv1);
          dacc(acc[i*3 + 2], qv, kv2);
        }
      }
      #pragma unroll
      for (int i = 0; i < 6; ++i) {
        const int q = q0 + i;
        if (q < 81) {
          const int qrow = q/9, qcol = q - qrow*9;
          const int qbox = (qrow/3)*3 + qcol/3;
          #pragma unroll
          for (int jj = 0; jj < 3; ++jj) {
            const int k = kc0 + jj;
            if (k < 81) {
              const int krow = k/9, kcol = k - krow*9;
              const int kbox = (krow/3)*3 + kcol/3;
              float msk = (h==0) ? (qrow==krow ? 1.f : 0.f)
                        : (h==1) ? (qcol==kcol ? 1.f : 0.f)
                        : (h==2) ? (qbox==kbox ? 1.f : 0.f)
                                 : 1.f;
              sc[q*84 + k] = acc[i*3 + jj] / 5.656854249492381f + msk;
            }
          }
        }
      }
    }
    __syncthreads();

    // ---- softmax: 6 threads per row
    if (tid < 486) {
      const int r = tid / 6, j = tid - (tid/6)*6;
      const int kb = j*14;
      float m = -INFINITY;
      for (int c = 0; c < 14; ++c) {
        int k = kb + c;
        if (k < 81) m = fmaxf(m, sc[r*84 + k]);
      }
      red[tid] = m;
    }
    __syncthreads();
    if (tid < 81) {
      float m = red[tid*6];
      #pragma unroll
      for (int j = 1; j < 6; ++j) m = fmaxf(m, red[tid*6 + j]);
      rmax[tid] = m;
    }
    __syncthreads();
    if (tid < 486) {
      const int r = tid / 6, j = tid - (tid/6)*6;
      const int kb = j*14;
      const float m = rmax[r];
      float ssum = 0.f;
      for (int c = 0; c < 14; ++c) {
        int k = kb + c;
        if (k < 81) ssum += expf(sc[r*84 + k] - m);
      }
      red[tid] = ssum;
    }
    __syncthreads();
    if (tid < 81) {
      float ssum = 0.f;
      #pragma unroll
      for (int j = 0; j < 6; ++j) ssum += red[tid*6 + j];
      rinv[tid] = 1.0f / ssum;
      sc[tid*84 + 81] = 0.f; sc[tid*84 + 82] = 0.f; sc[tid*84 + 83] = 0.f;
    }
    __syncthreads();

    // ---- probs in place + asc register accumulation
    #pragma unroll
    for (int i = 0; i < 13; ++i) {
      const int idx = tid + i*512;
      if (idx < 6561) {
        const int q = idx / 81, k = idx - q*81;
        float a = expf(sc[q*84 + k] - rmax[q]) * rinv[q];
        sc[q*84 + k] = a;
        ascR[i] += a;
      }
    }
    __syncthreads();

    // ---- ctx: n = (tid&31)*3+{0,1,2}, j = (tid>>5)*2+{0,1}; dot over k
    {
      const int ng = tid & 31, jg = tid >> 5;
      const int nb = ng*3, jb = jg*2;
      float a00=0.f, a01=0.f, a10=0.f, a11=0.f, a20=0.f, a21=0.f;
      const float* v0p = vL + jb*84;
      const float* v1p = vL + (jb+1)*84;
      const float* p0p = sc + nb*84;
      const float* p1p = sc + (nb+1)*84;
      const float* p2p = sc + (nb+2)*84;
      for (int k4 = 0; k4 < 21; ++k4) {
        const int ko = k4*4;
        float4 v0 = *(const float4*)(v0p + ko);
        float4 v1 = *(const float4*)(v1p + ko);
        float4 p0 = *(const float4*)(p0p + ko);
        float4 p1 = *(const float4*)(p1p + ko);
        float4 p2 = *(const float4*)(p2p + ko);
        dacc(a00, p0, v0); dacc(a01, p0, v1);
        dacc(a10, p1, v0); dacc(a11, p1, v1);
        dacc(a20, p2, v0); dacc(a21, p2, v1);
      }
      float* cb = ctxg + ((size_t)b*128 + h*32)*81;
      if (nb   < 81) { cb[jb*81 + nb]       = a00;
                       cb[(jb+1)*81 + nb]   = a01; }
      if (nb+1 < 81) { cb[jb*81 + nb+1]     = a10;
                       cb[(jb+1)*81 + nb+1] = a11; }
      if (nb+2 < 81) { cb[jb*81 + nb+2]     = a20;
                       cb[(jb+1)*81 + nb+2] = a21; }
    }
    __syncthreads();
  } // heads

  // asc = mean over heads, single coalesced write
  #pragma unroll
  for (int i = 0; i < 13; ++i) {
    const int idx = tid + i*512;
    if (idx < 6561) asc[(size_t)b*6561 + idx] = 0.25f * ascR[i];
  }
}

// ---------------- post: out-proj, LN, l1, l2, heads + sampling -------------
__global__ __launch_bounds__(256) void k_post(
    const float* __restrict__ ctxg,
    const float* __restrict__ owT,  const float* __restrict__ out_b,
    const float* __restrict__ ln_g, const float* __restrict__ ln_b,
    const float* __restrict__ l1T,  const float* __restrict__ l1_b,
    const float* __restrict__ l2T,  const float* __restrict__ l2_b,
    const float* __restrict__ pos_w, const float* __restrict__ pos_b,
    const float* __restrict__ num_w, const float* __restrict__ num_b,
    const int* __restrict__ digits,  float* __restrict__ dout)
{
  __shared__ float yT[128*84];
  __shared__ float red[243];
  __shared__ float mu[81], rstd[81];
  __shared__ float vals[81];
  __shared__ int   posIdx;
  const int b   = blockIdx.x;
  const int tid = threadIdx.x;
  const int ocg = tid >> 3;   // 0..31
  const int ng  = tid & 7;    // 0..7 (ng==7 idle in GEMMs)

  // stage ctx (global [b][128][81]) -> yT[k][n]; zero pad cols 81..83
  {
    const float* cb = ctxg + (size_t)b*128*81;
    for (int i = tid; i < 128*81; i += 256) {
      int k = i / 81, n = i - k*81;
      yT[k*84 + n] = cb[i];
    }
    for (int i = tid; i < 128*3; i += 256) {
      int k = i / 3, c = i - k*3;
      yT[k*84 + 81 + c] = 0.f;
    }
  }
  __syncthreads();

  // ---- out projection (reads yT as ctx, writes yT as y) ----
  {
    float4 acc[4][3];
    #pragma unroll
    for (int c = 0; c < 4; ++c)
      { acc[c][0]=zero4(); acc[c][1]=zero4(); acc[c][2]=zero4(); }
    if (ng < 7) {
      for (int k = 0; k < 128; ++k) {
        const float4 wv = *(const float4*)(owT + k*128 + ocg*4);
        const float* yr = yT + k*84 + ng*12;
        float4 x0 = *(const float4*)(yr);
        float4 x1 = *(const float4*)(yr + 4);
        float4 x2 = *(const float4*)(yr + 8);
        fma4b(acc[0][0], wv.x, x0); fma4b(acc[0][1], wv.x, x1); fma4b(acc[0][2], wv.x, x2);
        fma4b(acc[1][0], wv.y, x0); fma4b(acc[1][1], wv.y, x1); fma4b(acc[1][2], wv.y, x2);
        fma4b(acc[2][0], wv.z, x0); fma4b(acc[2][1], wv.z, x1); fma4b(acc[2][2], wv.z, x2);
        fma4b(acc[3][0], wv.w, x0); fma4b(acc[3][1], wv.w, x1); fma4b(acc[3][2], wv.w, x2);
      }
    }
    __syncthreads();
    if (ng < 7) {
      #pragma unroll
      for (int c = 0; c < 4; ++c) {
        const float bv = out_b[ocg*4 + c];
        #pragma unroll
        for (int t = 0; t < 3; ++t) {
          float4 o = acc[c][t];
          o.x += bv; o.y += bv; o.z += bv; o.w += bv;
          *(float4*)(yT + (ocg*4 + c)*84 + ng*12 + t*4) = o;
        }
      }
    }
  }
  __syncthreads();

  // ---- LayerNorm over k (columns n) ----
  if (tid < 243) {
    const int n = tid/3, j = tid - (tid/3)*3;
    float ssum = 0.f;
    for (int c = 0; c < 43; ++c) {
      int k = j*43 + c;
      if (k < 128) ssum += yT[k*84 + n];
    }
    red[tid] = ssum;
  }
  __syncthreads();
  if (tid < 81)
    mu[tid] = (red[tid*3] + red[tid*3+1] + red[tid*3+2]) * (1.0f/128.0f);
  __syncthreads();
  if (tid < 243) {
    const int n = tid/3, j = tid - (tid/3)*3;
    const float m = mu[n];
    float ssum = 0.f;
    for (int c = 0; c < 43; ++c) {
      int k = j*43 + c;
      if (k < 128) { float d = yT[k*84 + n] - m; ssum += d*d; }
    }
    red[tid] = ssum;
  }
  __syncthreads();
  if (tid < 81) {
    float v = (red[tid*3] + red[tid*3+1] + red[tid*3+2]) * (1.0f/128.0f);
    rstd[tid] = 1.0f / sqrtf(v + 1e-5f);
  }
  __syncthreads();
  for (int i = tid; i < 128*81; i += 256) {
    const int k = i / 81, n = i - k*81;
    yT[k*84 + n] = (yT[k*84 + n] - mu[n]) * rstd[n] * ln_g[k] + ln_b[k];
  }
  __syncthreads();

  // ---- l1 (silu) ----
  {
    float4 acc[4][3];
    #pragma unroll
    for (int c = 0; c < 4; ++c)
      { acc[c][0]=zero4(); acc[c][1]=zero4(); acc[c][2]=zero4(); }
    if (ng < 7) {
      for (int k = 0; k < 128; ++k) {
        const float4 wv = *(const float4*)(l1T + k*128 + ocg*4);
        const float* yr = yT + k*84 + ng*12;
        float4 x0 = *(const float4*)(yr);
        float4 x1 = *(const float4*)(yr + 4);
        float4 x2 = *(const float4*)(yr + 8);
        fma4b(acc[0][0], wv.x, x0); fma4b(acc[0][1], wv.x, x1); fma4b(acc[0][2], wv.x, x2);
        fma4b(acc[1][0], wv.y, x0); fma4b(acc[1][1], wv.y, x1); fma4b(acc[1][2], wv.y, x2);
        fma4b(acc[2][0], wv.z, x0); fma4b(acc[2][1], wv.z, x1); fma4b(acc[2][2], wv.z, x2);
        fma4b(acc[3][0], wv.w, x0); fma4b(acc[3][1], wv.w, x1); fma4b(acc[3][2], wv.w, x2);
      }
    }
    __syncthreads();
    if (ng < 7) {
      #pragma unroll
      for (int c = 0; c < 4; ++c) {
        const float bv = l1_b[ocg*4 + c];
        #pragma unroll
        for (int t = 0; t < 3; ++t) {
          float4 o = acc[c][t];
          o.x = silu_f(o.x + bv); o.y = silu_f(o.y + bv);
          o.z = silu_f(o.z + bv); o.w = silu_f(o.w + bv);
          *(float4*)(yT + (ocg*4 + c)*84 + ng*12 + t*4) = o;
        }
      }
    }
  }
  __syncthreads();

  // ---- l2 (silu) ----
  {
    float4 acc[4][3];
    #pragma unroll
    for (int c = 0; c < 4; ++c)
      { acc[c][0]=zero4(); acc[c][1]=zero4(); acc[c][2]=zero4(); }
    if (ng < 7) {
      for (int k = 0; k < 128; ++k) {
        const float4 wv = *(const float4*)(l2T + k*128 + ocg*4);
        const float* yr = yT + k*84 + ng*12;
        float4 x0 = *(const float4*)(yr);
        float4 x1 = *(const float4*)(yr + 4);
        float4 x2 = *(const float4*)(yr + 8);
        fma4b(acc[0][0], wv.x, x0); fma4b(acc[0][1], wv.x, x1); fma4b(acc[0][2], wv.x, x2);
        fma4b(acc[1][0], wv.y, x0); fma4b(acc[1][1], wv.y, x1); fma4b(acc[1][2], wv.y, x2);
        fma4b(acc[2][0], wv.z, x0); fma4b(acc[2][1], wv.z, x1); fma4b(acc[2][2], wv.z, x2);
        fma4b(acc[3][0], wv.w, x0); fma4b(acc[3][1], wv.w, x1); fma4b(acc[3][2], wv.w, x2);
      }
    }
    __syncthreads();
    if (ng < 7) {
      #pragma unroll
      for (int c = 0; c < 4; ++c) {
        const float bv = l2_b[ocg*4 + c];
        #pragma unroll
        for (int t = 0; t < 3; ++t) {
          float4 o = acc[c][t];
          o.x = silu_f(o.x + bv); o.y = silu_f(o.y + bv);
          o.z = silu_f(o.z + bv); o.w = silu_f(o.w + bv);
          *(float4*)(yT + (ocg*4 + c)*84 + ng*12 + t*4) = o;
        }
      }
    }
  }
  __syncthreads();

  // ---- position head + gumbel sampling ----
  uint32_t k1a, k1b, k2a, k2b;
  jax_split42(k1a, k1b, k2a, k2b);

  if (tid < 243) {
    const int n = tid/3, j = tid - (tid/3)*3;
    float ssum = 0.f;
    for (int c = 0; c < 43; ++c) {
      int k = j*43 + c;
      if (k < 128) ssum += yT[k*84 + n] * pos_w[k];
    }
    red[tid] = ssum;
  }
  __syncthreads();
  if (tid < 81) {
    float acc = red[tid*3] + red[tid*3+1] + red[tid*3+2] + pos_b[0];
    if (digits[b*81 + tid] != 0) acc = -1e9f;
    uint32_t bits = jax_randbits(k1a, k1b, (uint32_t)(b*81 + tid));
    vals[tid] = acc + jax_gumbel_bits(bits);
  }
  __syncthreads();
  if (tid == 0) {
    float best = vals[0]; int bi = 0;
    for (int n = 1; n < 81; ++n)
      if (vals[n] > best) { best = vals[n]; bi = n; }
    posIdx = bi;
    dout[b] = (float)bi;
  }
  __syncthreads();
  const int pos = posIdx;

  // ---- number head at sampled position ----
  if (tid < 80) {
    const int d = tid >> 3, j = tid & 7;
    float ssum = 0.f;
    #pragma unroll
    for (int c = 0; c < 16; ++c) {
      int k = j*16 + c;
      ssum += yT[k*84 + pos] * num_w[d*128 + k];
    }
    red[tid] = ssum;
  }
  __syncthreads();
  if (tid < 10) {
    float acc = num_b[tid];
    #pragma unroll
    for (int j = 0; j < 8; ++j) acc += red[tid*8 + j];
    if (tid == 0) acc = -INFINITY;
    uint32_t bits = jax_randbits(k2a, k2b, (uint32_t)(b*10 + tid));
    vals[tid] = acc + jax_gumbel_bits(bits);
  }
  __syncthreads();
  if (tid == 0) {
    float best = vals[0]; int bi = 0;
    for (int d = 1; d < 10; ++d)
      if (vals[d] > best) { best = vals[d]; bi = d; }
    dout[NB + b] = (float)bi;
  }
}

// ---------------------------------------------------------------------------
extern "C" void kernel_launch(void* const* d_in, const int* in_sizes, int n_in,
                              void* d_out, int out_size, void* d_ws, size_t ws_size,
                              hipStream_t stream) {
  const float* s     = (const float*)d_in[0];
  const float* c1_w  = (const float*)d_in[1];
  const float* c1_b  = (const float*)d_in[2];
  const float* c2_w  = (const float*)d_in[3];
  const float* c2_b  = (const float*)d_in[4];
  const float* c3_w  = (const float*)d_in[5];
  const float* c3_b  = (const float*)d_in[6];
  const float* emb   = (const float*)d_in[7];
  const float* in_w  = (const float*)d_in[8];
  const float* in_b  = (const float*)d_in[9];
  const float* out_w = (const float*)d_in[10];
  const float* out_b = (const float*)d_in[11];
  const float* ln_g  = (const float*)d_in[12];
  const float* ln_b  = (const float*)d_in[13];
  const float* l1_w  = (const float*)d_in[14];
  const float* l1_b  = (const float*)d_in[15];
  const float* l2_w  = (const float*)d_in[16];
  const float* l2_b  = (const float*)d_in[17];
  const float* pos_w = (const float*)d_in[18];
  const float* pos_b = (const float*)d_in[19];
  const float* num_w = (const float*)d_in[20];
  const float* num_b = (const float*)d_in[21];

  // ws layout (floats):
  // T2e 0 (12672) | w3r 12672 (147456) | owT 160128 (16384) |
  // l1T 176512 (16384) | l2T 192896 (16384) | digits 209280 (331776 int) |
  // x 541056 (42467328) | ctxg 43008384 (42467328)
  float* ws     = (float*)d_ws;
  float* T2e    = ws;
  float* w3r    = ws + 12672;
  float* owT    = ws + 160128;
  float* l1T    = ws + 176512;
  float* l2T    = ws + 192896;
  int*   digits = (int*)(ws + 209280);
  float* x      = ws + 541056;
  float* ctxg   = ws + 43008384;

  float* dout = (float*)d_out;
  float* asc  = dout + 2*NB;

  hipFuncSetAttribute((const void*)k_attn,
                      hipFuncAttributeMaxDynamicSharedMemorySize,
                      ATTN_LDS_BYTES);

  k_prep<<<dim3(818), dim3(256), 0, stream>>>(
      c1_w, c1_b, c2_w, c3_w, out_w, l1_w, l2_w,
      T2e, w3r, owT, l1T, l2T);
  k_stem<<<dim3(NB), dim3(256), 0, stream>>>(
      s, T2e, c2_b, w3r, c3_b, emb, x, digits);
  k_attn<<<dim3(NB), dim3(512), ATTN_LDS_BYTES, stream>>>(
      x, in_w, in_b, ctxg, asc);
  k_post<<<dim3(NB), dim3(256), 0, stream>>>(
      ctxg, owT, out_b, ln_g, ln_b, l1T, l1_b, l2T, l2_b,
      pos_w, pos_b, num_w, num_b, digits, dout);
}

// Round 5
// 5071.280 us; speedup vs baseline: 2.4890x; 1.5396x over previous
//
#include <hip/hip_runtime.h>
#include <stdint.h>
#include <math.h>

// ---------------------------------------------------------------------------
// p_net forward on MI355X.  B=4096 boards, N=81 cells, D=128, H=4 heads.
// Round 5: k_attn spill kill, attempt 2.
//   - __launch_bounds__(512) only: HW cap for 512-thr block is 256 VGPR;
//     round-4's (512,2) produced a 128 cap (16-wave/CU budget) and spills.
//   - #pragma unroll 2 on QKV/scores/ctx k-loops: stops full unroll from
//     keeping ~192 global loads in flight and spilling accumulators.
// Outputs (concat, float32): pos[4096], num[4096], asc[4096*81*81].
// ---------------------------------------------------------------------------

#define NB 4096

__device__ __forceinline__ float silu_f(float v) {
  return v / (1.0f + expf(-v));
}

__device__ __forceinline__ float4 zero4() { return make_float4(0.f,0.f,0.f,0.f); }

__device__ __forceinline__ void fma4b(float4& a, const float s, const float4 x) {
  a.x = fmaf(s, x.x, a.x); a.y = fmaf(s, x.y, a.y);
  a.z = fmaf(s, x.z, a.z); a.w = fmaf(s, x.w, a.w);
}

// sequential dot-accumulate: a += w·x, 4 fmaf, scalar accumulator
__device__ __forceinline__ void dacc(float& a, const float4 w, const float4 x) {
  a = fmaf(w.x, x.x, a); a = fmaf(w.y, x.y, a);
  a = fmaf(w.z, x.z, a); a = fmaf(w.w, x.w, a);
}

// ---------------- Threefry-2x32 (JAX partitionable) ------------------------
__device__ __forceinline__ void tf_round(uint32_t& x0, uint32_t& x1, int r) {
  x0 += x1;
  x1 = (x1 << r) | (x1 >> (32 - r));
  x1 ^= x0;
}

__device__ __forceinline__ void threefry2x32(uint32_t k0, uint32_t k1,
                                             uint32_t x0, uint32_t x1,
                                             uint32_t& o0, uint32_t& o1) {
  uint32_t k2 = k0 ^ k1 ^ 0x1BD11BDAu;
  x0 += k0; x1 += k1;
  tf_round(x0,x1,13); tf_round(x0,x1,15); tf_round(x0,x1,26); tf_round(x0,x1,6);
  x0 += k1; x1 += k2 + 1u;
  tf_round(x0,x1,17); tf_round(x0,x1,29); tf_round(x0,x1,16); tf_round(x0,x1,24);
  x0 += k2; x1 += k0 + 2u;
  tf_round(x0,x1,13); tf_round(x0,x1,15); tf_round(x0,x1,26); tf_round(x0,x1,6);
  x0 += k0; x1 += k1 + 3u;
  tf_round(x0,x1,17); tf_round(x0,x1,29); tf_round(x0,x1,16); tf_round(x0,x1,24);
  x0 += k1; x1 += k2 + 4u;
  tf_round(x0,x1,13); tf_round(x0,x1,15); tf_round(x0,x1,26); tf_round(x0,x1,6);
  x0 += k2; x1 += k0 + 5u;
  o0 = x0; o1 = x1;
}

__device__ __forceinline__ void jax_split42(uint32_t& k1a, uint32_t& k1b,
                                            uint32_t& k2a, uint32_t& k2b) {
  threefry2x32(0u, 42u, 0u, 0u, k1a, k1b);
  threefry2x32(0u, 42u, 0u, 1u, k2a, k2b);
}

__device__ __forceinline__ uint32_t jax_randbits(uint32_t ka, uint32_t kb,
                                                 uint32_t i) {
  uint32_t o0, o1;
  threefry2x32(ka, kb, 0u, i, o0, o1);
  return o0 ^ o1;
}

__device__ __forceinline__ float jax_gumbel_bits(uint32_t bits) {
  float f = __uint_as_float((bits >> 9) | 0x3f800000u) - 1.0f;
  const float tiny = 1.17549435e-38f;
  float u = fmaxf(tiny, f + tiny);
  return -logf(-logf(u));
}

// ---------------- prep: conv tables + weight transposes --------------------
__global__ __launch_bounds__(256) void k_prep(
    const float* __restrict__ c1_w, const float* __restrict__ c1_b,
    const float* __restrict__ c2_w, const float* __restrict__ c3_w,
    const float* __restrict__ out_w, const float* __restrict__ l1_w,
    const float* __restrict__ l2_w,
    float* __restrict__ T2e, float* __restrict__ w3r,
    float* __restrict__ owT, float* __restrict__ l1T, float* __restrict__ l2T)
{
  int idx = blockIdx.x * 256 + threadIdx.x;
  if (idx < 9*11*128) {
    int oc = idx & 127;
    int t  = idx >> 7;
    int g  = t % 11;
    int d  = t / 11;
    float acc = 0.f;
    if (g < 10) {
      int di = d / 3, dj = d % 3;
      for (int ic = 0; ic < 64; ++ic) {
        float x1 = c1_w[ic*10 + g] + c1_b[ic];
        acc += c2_w[((oc*64 + ic)*3 + di)*3 + dj] * x1;
      }
    }
    T2e[idx] = acc;
  } else if (idx < 160128) {
    int j  = idx - 12672;
    int ic = j & 127;
    int t  = j >> 7;
    int oc = t & 127;
    int d  = t >> 7;
    w3r[j] = c3_w[(oc*128 + ic)*9 + d];
  } else if (idx < 176512) {
    int j = idx - 160128;                      // j = k*128 + oc
    owT[j] = out_w[(j & 127)*128 + (j >> 7)];
  } else if (idx < 192896) {
    int j = idx - 176512;
    l1T[j] = l1_w[(j & 127)*128 + (j >> 7)];
  } else if (idx < 209280) {
    int j = idx - 192896;
    l2T[j] = l2_w[(j & 127)*128 + (j >> 7)];
  }
}

// ---------------- stem: digits -> conv2(table) -> conv3 -> +emb ------------
__global__ __launch_bounds__(256) void k_stem(
    const float* __restrict__ s, const float* __restrict__ T2e,
    const float* __restrict__ c2_b, const float* __restrict__ w3r,
    const float* __restrict__ c3_b, const float* __restrict__ emb,
    float* __restrict__ xout, int* __restrict__ digits)
{
  __shared__ float x2s[121*128];
  __shared__ int   dg[121];
  const int b   = blockIdx.x;
  const int tid = threadIdx.x;

  for (int i = tid; i < (121*128)/4; i += 256)
    ((float4*)x2s)[i] = make_float4(0.f, 0.f, 0.f, 0.f);
  if (tid < 121) dg[tid] = 10;
  __syncthreads();

  if (tid < 81) {
    const float* sp = s + (size_t)b*810 + tid;
    float dv = 0.f;
    #pragma unroll
    for (int c = 1; c < 10; ++c) dv += (float)c * sp[c*81];
    int d = (int)(dv + 0.5f);
    dg[(tid/9 + 1)*11 + (tid%9 + 1)] = d;
    digits[b*81 + tid] = d;
  }
  __syncthreads();

  const int oc4 = (tid & 31) * 4;
  const int cg  = tid >> 5;

  {
    const float4 bias = *(const float4*)(c2_b + oc4);
    for (int ci = 0; ci < 11; ++ci) {
      int c  = cg*11 + ci;
      int rc = (c < 81) ? c : 0;
      int i = rc/9, j = rc%9;
      float4 a = bias;
      #pragma unroll
      for (int d = 0; d < 9; ++d) {
        int g = dg[(i + d/3)*11 + (j + d%3)];
        const float4 t = *(const float4*)(T2e + (d*11 + g)*128 + oc4);
        a.x += t.x; a.y += t.y; a.z += t.z; a.w += t.w;
      }
      a.x = silu_f(a.x); a.y = silu_f(a.y); a.z = silu_f(a.z); a.w = silu_f(a.w);
      if (c < 81)
        *(float4*)(x2s + ((i+1)*11 + (j+1))*128 + oc4) = a;
    }
  }
  __syncthreads();

  {
    float acc[11][4];
    #pragma unroll
    for (int ci = 0; ci < 11; ++ci) {
      acc[ci][0] = 0.f; acc[ci][1] = 0.f; acc[ci][2] = 0.f; acc[ci][3] = 0.f;
    }
    int pb[11];
    #pragma unroll
    for (int ci = 0; ci < 11; ++ci) {
      int c  = cg*11 + ci;
      int rc = (c < 81) ? c : 0;
      pb[ci] = (rc/9)*11 + (rc%9);
    }
    for (int d = 0; d < 9; ++d) {
      const int off = (d/3)*11 + (d%3);
      const float* wbase = w3r + (size_t)(d*128 + oc4)*128;
      for (int k = 0; k < 128; k += 4) {
        const float4 w0 = *(const float4*)(wbase + k);
        const float4 w1 = *(const float4*)(wbase + 128 + k);
        const float4 w2 = *(const float4*)(wbase + 256 + k);
        const float4 w3 = *(const float4*)(wbase + 384 + k);
        #pragma unroll
        for (int ci = 0; ci < 11; ++ci) {
          const float4 xv = *(const float4*)(x2s + (pb[ci] + off)*128 + k);
          acc[ci][0] += w0.x*xv.x + w0.y*xv.y + w0.z*xv.z + w0.w*xv.w;
          acc[ci][1] += w1.x*xv.x + w1.y*xv.y + w1.z*xv.z + w1.w*xv.w;
          acc[ci][2] += w2.x*xv.x + w2.y*xv.y + w2.z*xv.z + w2.w*xv.w;
          acc[ci][3] += w3.x*xv.x + w3.y*xv.y + w3.z*xv.z + w3.w*xv.w;
        }
      }
    }
    const float4 b3 = *(const float4*)(c3_b + oc4);
    #pragma unroll
    for (int ci = 0; ci < 11; ++ci) {
      int c = cg*11 + ci;
      if (c < 81) {
        const float4 e = *(const float4*)(emb + c*128 + oc4);
        float4 o;
        o.x = silu_f(acc[ci][0] + b3.x) + e.x;
        o.y = silu_f(acc[ci][1] + b3.y) + e.y;
        o.z = silu_f(acc[ci][2] + b3.z) + e.z;
        o.w = silu_f(acc[ci][3] + b3.w) + e.w;
        *(float4*)(xout + ((size_t)b*81 + c)*128 + oc4) = o;
      }
    }
  }
}

// ---------------- attention ------------------------------------------------
// 512 threads / board. Dynamic LDS layout (floats):
//  xL   @ 0      [81][132]  staged board activations (row-major, k-contig)
//  qkT  @ 10692  [84][68]   q,k cell-major: qkT[cell][m], m 0..31 q, 32..63 k
//  vL   @ 16404  [32][84]   v row-major: vL[j][cell]
//  sc   @ 19092  [81][84]   scores -> probs (pad cols zeroed)
//  red  @ 25896  [486]      softmax partials
//  rmax @ 26544  [81]
//  rinv @ 26625  [81]
#define ATTN_LDS_BYTES (27392*4)

__global__ __launch_bounds__(512) void k_attn(
    const float* __restrict__ x, const float* __restrict__ in_w,
    const float* __restrict__ in_b, float* __restrict__ ctxg,
    float* __restrict__ asc)
{
  extern __shared__ float sm[];
  float* xL   = sm;
  float* qkT  = sm + 10692;
  float* vL   = sm + 16404;
  float* sc   = sm + 19092;
  float* red  = sm + 25896;
  float* rmax = sm + 26544;
  float* rinv = sm + 26625;

  const int b   = blockIdx.x;
  const int tid = threadIdx.x;
  const int rg  = tid >> 5;     // 0..15
  const int cg  = tid & 31;     // 0..31

  // stage x -> xL (coalesced global float4)
  {
    const float4* xg = (const float4*)(x + (size_t)b*81*128);
    for (int i = tid; i < 81*32; i += 512) {
      int n = i >> 5, k4 = i & 31;
      *(float4*)(xL + n*132 + k4*4) = xg[n*32 + k4];
    }
  }

  float ascR[13];
  #pragma unroll
  for (int i = 0; i < 13; ++i) ascR[i] = 0.f;

  __syncthreads();

  for (int h = 0; h < 4; ++h) {
    // ---- QKV: rows m = rg*6+i (0..95), cells n = cg + {0,32,64}
    // scalar accumulators; unroll 2 to bound in-flight load count (no spill)
    {
      float acc[18];
      #pragma unroll
      for (int i = 0; i < 18; ++i) acc[i] = 0.f;
      int rows[6];
      #pragma unroll
      for (int i = 0; i < 6; ++i) {
        int m = rg*6 + i;
        rows[i] = (m < 32) ? (h*32 + m)
                : (m < 64) ? (128 + h*32 + (m - 32))
                           : (256 + h*32 + (m - 64));
      }
      const float* x0p = xL + cg*132;
      const float* x1p = xL + (cg+32)*132;
      const float* x2p = xL + (cg+64)*132;
      #pragma unroll 2
      for (int k4 = 0; k4 < 32; ++k4) {
        const int ko = k4*4;
        float4 x0 = *(const float4*)(x0p + ko);
        float4 x1 = *(const float4*)(x1p + ko);
        float4 x2 = *(const float4*)(x2p + ko);
        #pragma unroll
        for (int i = 0; i < 6; ++i) {
          float4 w = *(const float4*)(in_w + rows[i]*128 + ko);
          dacc(acc[i*3 + 0], w, x0);
          dacc(acc[i*3 + 1], w, x1);
          dacc(acc[i*3 + 2], w, x2);
        }
      }
      #pragma unroll
      for (int i = 0; i < 6; ++i) {
        const int m = rg*6 + i;
        const float bias = in_b[rows[i]];
        float s0 = acc[i*3 + 0] + bias;
        float s1 = acc[i*3 + 1] + bias;
        float s2 = acc[i*3 + 2] + bias;
        if (m < 64) {
          qkT[cg*68 + m]      = s0;
          qkT[(cg+32)*68 + m] = s1;
          if (cg+64 < 81) qkT[(cg+64)*68 + m] = s2;
        } else {
          const int j = m - 64;
          vL[j*84 + cg]      = s0;
          vL[j*84 + cg+32]   = s1;
          if (cg+64 < 81)      vL[j*84 + cg+64] = s2;
          else if (cg+64 < 84) vL[j*84 + cg+64] = 0.f;   // zero pad cols
        }
      }
    }
    __syncthreads();

    // ---- scores: q = rg*6+i, k = cg*3+jj, dot over m=32
    {
      float acc[18];
      #pragma unroll
      for (int i = 0; i < 18; ++i) acc[i] = 0.f;
      const int q0 = rg*6, kc0 = cg*3;
      #pragma unroll 2
      for (int m4 = 0; m4 < 8; ++m4) {
        const int mo = m4*4;
        float4 kv0 = *(const float4*)(qkT + (kc0+0)*68 + 32 + mo);
        float4 kv1 = *(const float4*)(qkT + (kc0+1)*68 + 32 + mo);
        float4 kv2 = *(const float4*)(qkT + (kc0+2)*68 + 32 + mo);
        #pragma unroll
        for (int i = 0; i < 6; ++i) {
          float4 qv = *(const float4*)(qkT + (q0+i)*68 + mo);
          dacc(acc[i*3 + 0], qv, kv0);
          dacc(acc[i*3 + 1], qv, kv1);
          dacc(acc[i*3 + 2], qv, kv2);
        }
      }
      #pragma unroll
      for (int i = 0; i < 6; ++i) {
        const int q = q0 + i;
        if (q < 81) {
          const int qrow = q/9, qcol = q - qrow*9;
          const int qbox = (qrow/3)*3 + qcol/3;
          #pragma unroll
          for (int jj = 0; jj < 3; ++jj) {
            const int k = kc0 + jj;
            if (k < 81) {
              const int krow = k/9, kcol = k - krow*9;
              const int kbox = (krow/3)*3 + kcol/3;
              float msk = (h==0) ? (qrow==krow ? 1.f : 0.f)
                        : (h==1) ? (qcol==kcol ? 1.f : 0.f)
                        : (h==2) ? (qbox==kbox ? 1.f : 0.f)
                                 : 1.f;
              sc[q*84 + k] = acc[i*3 + jj] / 5.656854249492381f + msk;
            }
          }
        }
      }
    }
    __syncthreads();

    // ---- softmax: 6 threads per row
    if (tid < 486) {
      const int r = tid / 6, j = tid - (tid/6)*6;
      const int kb = j*14;
      float m = -INFINITY;
      for (int c = 0; c < 14; ++c) {
        int k = kb + c;
        if (k < 81) m = fmaxf(m, sc[r*84 + k]);
      }
      red[tid] = m;
    }
    __syncthreads();
    if (tid < 81) {
      float m = red[tid*6];
      #pragma unroll
      for (int j = 1; j < 6; ++j) m = fmaxf(m, red[tid*6 + j]);
      rmax[tid] = m;
    }
    __syncthreads();
    if (tid < 486) {
      const int r = tid / 6, j = tid - (tid/6)*6;
      const int kb = j*14;
      const float m = rmax[r];
      float ssum = 0.f;
      for (int c = 0; c < 14; ++c) {
        int k = kb + c;
        if (k < 81) ssum += expf(sc[r*84 + k] - m);
      }
      red[tid] = ssum;
    }
    __syncthreads();
    if (tid < 81) {
      float ssum = 0.f;
      #pragma unroll
      for (int j = 0; j < 6; ++j) ssum += red[tid*6 + j];
      rinv[tid] = 1.0f / ssum;
      sc[tid*84 + 81] = 0.f; sc[tid*84 + 82] = 0.f; sc[tid*84 + 83] = 0.f;
    }
    __syncthreads();

    // ---- probs in place + asc register accumulation
    #pragma unroll
    for (int i = 0; i < 13; ++i) {
      const int idx = tid + i*512;
      if (idx < 6561) {
        const int q = idx / 81, k = idx - q*81;
        float a = expf(sc[q*84 + k] - rmax[q]) * rinv[q];
        sc[q*84 + k] = a;
        ascR[i] += a;
      }
    }
    __syncthreads();

    // ---- ctx: n = (tid&31)*3+{0,1,2}, j = (tid>>5)*2+{0,1}; dot over k
    {
      const int ng = tid & 31, jg = tid >> 5;
      const int nb = ng*3, jb = jg*2;
      float a00=0.f, a01=0.f, a10=0.f, a11=0.f, a20=0.f, a21=0.f;
      const float* v0p = vL + jb*84;
      const float* v1p = vL + (jb+1)*84;
      const float* p0p = sc + nb*84;
      const float* p1p = sc + (nb+1)*84;
      const float* p2p = sc + (nb+2)*84;
      #pragma unroll 2
      for (int k4 = 0; k4 < 21; ++k4) {
        const int ko = k4*4;
        float4 v0 = *(const float4*)(v0p + ko);
        float4 v1 = *(const float4*)(v1p + ko);
        float4 p0 = *(const float4*)(p0p + ko);
        float4 p1 = *(const float4*)(p1p + ko);
        float4 p2 = *(const float4*)(p2p + ko);
        dacc(a00, p0, v0); dacc(a01, p0, v1);
        dacc(a10, p1, v0); dacc(a11, p1, v1);
        dacc(a20, p2, v0); dacc(a21, p2, v1);
      }
      float* cb = ctxg + ((size_t)b*128 + h*32)*81;
      if (nb   < 81) { cb[jb*81 + nb]       = a00;
                       cb[(jb+1)*81 + nb]   = a01; }
      if (nb+1 < 81) { cb[jb*81 + nb+1]     = a10;
                       cb[(jb+1)*81 + nb+1] = a11; }
      if (nb+2 < 81) { cb[jb*81 + nb+2]     = a20;
                       cb[(jb+1)*81 + nb+2] = a21; }
    }
    __syncthreads();
  } // heads

  // asc = mean over heads, single coalesced write
  #pragma unroll
  for (int i = 0; i < 13; ++i) {
    const int idx = tid + i*512;
    if (idx < 6561) asc[(size_t)b*6561 + idx] = 0.25f * ascR[i];
  }
}

// ---------------- post: out-proj, LN, l1, l2, heads + sampling -------------
__global__ __launch_bounds__(256) void k_post(
    const float* __restrict__ ctxg,
    const float* __restrict__ owT,  const float* __restrict__ out_b,
    const float* __restrict__ ln_g, const float* __restrict__ ln_b,
    const float* __restrict__ l1T,  const float* __restrict__ l1_b,
    const float* __restrict__ l2T,  const float* __restrict__ l2_b,
    const float* __restrict__ pos_w, const float* __restrict__ pos_b,
    const float* __restrict__ num_w, const float* __restrict__ num_b,
    const int* __restrict__ digits,  float* __restrict__ dout)
{
  __shared__ float yT[128*84];
  __shared__ float red[243];
  __shared__ float mu[81], rstd[81];
  __shared__ float vals[81];
  __shared__ int   posIdx;
  const int b   = blockIdx.x;
  const int tid = threadIdx.x;
  const int ocg = tid >> 3;   // 0..31
  const int ng  = tid & 7;    // 0..7 (ng==7 idle in GEMMs)

  // stage ctx (global [b][128][81]) -> yT[k][n]; zero pad cols 81..83
  {
    const float* cb = ctxg + (size_t)b*128*81;
    for (int i = tid; i < 128*81; i += 256) {
      int k = i / 81, n = i - k*81;
      yT[k*84 + n] = cb[i];
    }
    for (int i = tid; i < 128*3; i += 256) {
      int k = i / 3, c = i - k*3;
      yT[k*84 + 81 + c] = 0.f;
    }
  }
  __syncthreads();

  // ---- out projection (reads yT as ctx, writes yT as y) ----
  {
    float4 acc[4][3];
    #pragma unroll
    for (int c = 0; c < 4; ++c)
      { acc[c][0]=zero4(); acc[c][1]=zero4(); acc[c][2]=zero4(); }
    if (ng < 7) {
      #pragma unroll 2
      for (int k = 0; k < 128; ++k) {
        const float4 wv = *(const float4*)(owT + k*128 + ocg*4);
        const float* yr = yT + k*84 + ng*12;
        float4 x0 = *(const float4*)(yr);
        float4 x1 = *(const float4*)(yr + 4);
        float4 x2 = *(const float4*)(yr + 8);
        fma4b(acc[0][0], wv.x, x0); fma4b(acc[0][1], wv.x, x1); fma4b(acc[0][2], wv.x, x2);
        fma4b(acc[1][0], wv.y, x0); fma4b(acc[1][1], wv.y, x1); fma4b(acc[1][2], wv.y, x2);
        fma4b(acc[2][0], wv.z, x0); fma4b(acc[2][1], wv.z, x1); fma4b(acc[2][2], wv.z, x2);
        fma4b(acc[3][0], wv.w, x0); fma4b(acc[3][1], wv.w, x1); fma4b(acc[3][2], wv.w, x2);
      }
    }
    __syncthreads();
    if (ng < 7) {
      #pragma unroll
      for (int c = 0; c < 4; ++c) {
        const float bv = out_b[ocg*4 + c];
        #pragma unroll
        for (int t = 0; t < 3; ++t) {
          float4 o = acc[c][t];
          o.x += bv; o.y += bv; o.z += bv; o.w += bv;
          *(float4*)(yT + (ocg*4 + c)*84 + ng*12 + t*4) = o;
        }
      }
    }
  }
  __syncthreads();

  // ---- LayerNorm over k (columns n) ----
  if (tid < 243) {
    const int n = tid/3, j = tid - (tid/3)*3;
    float ssum = 0.f;
    for (int c = 0; c < 43; ++c) {
      int k = j*43 + c;
      if (k < 128) ssum += yT[k*84 + n];
    }
    red[tid] = ssum;
  }
  __syncthreads();
  if (tid < 81)
    mu[tid] = (red[tid*3] + red[tid*3+1] + red[tid*3+2]) * (1.0f/128.0f);
  __syncthreads();
  if (tid < 243) {
    const int n = tid/3, j = tid - (tid/3)*3;
    const float m = mu[n];
    float ssum = 0.f;
    for (int c = 0; c < 43; ++c) {
      int k = j*43 + c;
      if (k < 128) { float d = yT[k*84 + n] - m; ssum += d*d; }
    }
    red[tid] = ssum;
  }
  __syncthreads();
  if (tid < 81) {
    float v = (red[tid*3] + red[tid*3+1] + red[tid*3+2]) * (1.0f/128.0f);
    rstd[tid] = 1.0f / sqrtf(v + 1e-5f);
  }
  __syncthreads();
  for (int i = tid; i < 128*81; i += 256) {
    const int k = i / 81, n = i - k*81;
    yT[k*84 + n] = (yT[k*84 + n] - mu[n]) * rstd[n] * ln_g[k] + ln_b[k];
  }
  __syncthreads();

  // ---- l1 (silu) ----
  {
    float4 acc[4][3];
    #pragma unroll
    for (int c = 0; c < 4; ++c)
      { acc[c][0]=zero4(); acc[c][1]=zero4(); acc[c][2]=zero4(); }
    if (ng < 7) {
      #pragma unroll 2
      for (int k = 0; k < 128; ++k) {
        const float4 wv = *(const float4*)(l1T + k*128 + ocg*4);
        const float* yr = yT + k*84 + ng*12;
        float4 x0 = *(const float4*)(yr);
        float4 x1 = *(const float4*)(yr + 4);
        float4 x2 = *(const float4*)(yr + 8);
        fma4b(acc[0][0], wv.x, x0); fma4b(acc[0][1], wv.x, x1); fma4b(acc[0][2], wv.x, x2);
        fma4b(acc[1][0], wv.y, x0); fma4b(acc[1][1], wv.y, x1); fma4b(acc[1][2], wv.y, x2);
        fma4b(acc[2][0], wv.z, x0); fma4b(acc[2][1], wv.z, x1); fma4b(acc[2][2], wv.z, x2);
        fma4b(acc[3][0], wv.w, x0); fma4b(acc[3][1], wv.w, x1); fma4b(acc[3][2], wv.w, x2);
      }
    }
    __syncthreads();
    if (ng < 7) {
      #pragma unroll
      for (int c = 0; c < 4; ++c) {
        const float bv = l1_b[ocg*4 + c];
        #pragma unroll
        for (int t = 0; t < 3; ++t) {
          float4 o = acc[c][t];
          o.x = silu_f(o.x + bv); o.y = silu_f(o.y + bv);
          o.z = silu_f(o.z + bv); o.w = silu_f(o.w + bv);
          *(float4*)(yT + (ocg*4 + c)*84 + ng*12 + t*4) = o;
        }
      }
    }
  }
  __syncthreads();

  // ---- l2 (silu) ----
  {
    float4 acc[4][3];
    #pragma unroll
    for (int c = 0; c < 4; ++c)
      { acc[c][0]=zero4(); acc[c][1]=zero4(); acc[c][2]=zero4(); }
    if (ng < 7) {
      #pragma unroll 2
      for (int k = 0; k < 128; ++k) {
        const float4 wv = *(const float4*)(l2T + k*128 + ocg*4);
        const float* yr = yT + k*84 + ng*12;
        float4 x0 = *(const float4*)(yr);
        float4 x1 = *(const float4*)(yr + 4);
        float4 x2 = *(const float4*)(yr + 8);
        fma4b(acc[0][0], wv.x, x0); fma4b(acc[0][1], wv.x, x1); fma4b(acc[0][2], wv.x, x2);
        fma4b(acc[1][0], wv.y, x0); fma4b(acc[1][1], wv.y, x1); fma4b(acc[1][2], wv.y, x2);
        fma4b(acc[2][0], wv.z, x0); fma4b(acc[2][1], wv.z, x1); fma4b(acc[2][2], wv.z, x2);
        fma4b(acc[3][0], wv.w, x0); fma4b(acc[3][1], wv.w, x1); fma4b(acc[3][2], wv.w, x2);
      }
    }
    __syncthreads();
    if (ng < 7) {
      #pragma unroll
      for (int c = 0; c < 4; ++c) {
        const float bv = l2_b[ocg*4 + c];
        #pragma unroll
        for (int t = 0; t < 3; ++t) {
          float4 o = acc[c][t];
          o.x = silu_f(o.x + bv); o.y = silu_f(o.y + bv);
          o.z = silu_f(o.z + bv); o.w = silu_f(o.w + bv);
          *(float4*)(yT + (ocg*4 + c)*84 + ng*12 + t*4) = o;
        }
      }
    }
  }
  __syncthreads();

  // ---- position head + gumbel sampling ----
  uint32_t k1a, k1b, k2a, k2b;
  jax_split42(k1a, k1b, k2a, k2b);

  if (tid < 243) {
    const int n = tid/3, j = tid - (tid/3)*3;
    float ssum = 0.f;
    for (int c = 0; c < 43; ++c) {
      int k = j*43 + c;
      if (k < 128) ssum += yT[k*84 + n] * pos_w[k];
    }
    red[tid] = ssum;
  }
  __syncthreads();
  if (tid < 81) {
    float acc = red[tid*3] + red[tid*3+1] + red[tid*3+2] + pos_b[0];
    if (digits[b*81 + tid] != 0) acc = -1e9f;
    uint32_t bits = jax_randbits(k1a, k1b, (uint32_t)(b*81 + tid));
    vals[tid] = acc + jax_gumbel_bits(bits);
  }
  __syncthreads();
  if (tid == 0) {
    float best = vals[0]; int bi = 0;
    for (int n = 1; n < 81; ++n)
      if (vals[n] > best) { best = vals[n]; bi = n; }
    posIdx = bi;
    dout[b] = (float)bi;
  }
  __syncthreads();
  const int pos = posIdx;

  // ---- number head at sampled position ----
  if (tid < 80) {
    const int d = tid >> 3, j = tid & 7;
    float ssum = 0.f;
    #pragma unroll
    for (int c = 0; c < 16; ++c) {
      int k = j*16 + c;
      ssum += yT[k*84 + pos] * num_w[d*128 + k];
    }
    red[tid] = ssum;
  }
  __syncthreads();
  if (tid < 10) {
    float acc = num_b[tid];
    #pragma unroll
    for (int j = 0; j < 8; ++j) acc += red[tid*8 + j];
    if (tid == 0) acc = -INFINITY;
    uint32_t bits = jax_randbits(k2a, k2b, (uint32_t)(b*10 + tid));
    vals[tid] = acc + jax_gumbel_bits(bits);
  }
  __syncthreads();
  if (tid == 0) {
    float best = vals[0]; int bi = 0;
    for (int d = 1; d < 10; ++d)
      if (vals[d] > best) { best = vals[d]; bi = d; }
    dout[NB + b] = (float)bi;
  }
}

// ---------------------------------------------------------------------------
extern "C" void kernel_launch(void* const* d_in, const int* in_sizes, int n_in,
                              void* d_out, int out_size, void* d_ws, size_t ws_size,
                              hipStream_t stream) {
  const float* s     = (const float*)d_in[0];
  const float* c1_w  = (const float*)d_in[1];
  const float* c1_b  = (const float*)d_in[2];
  const float* c2_w  = (const float*)d_in[3];
  const float* c2_b  = (const float*)d_in[4];
  const float* c3_w  = (const float*)d_in[5];
  const float* c3_b  = (const float*)d_in[6];
  const float* emb   = (const float*)d_in[7];
  const float* in_w  = (const float*)d_in[8];
  const float* in_b  = (const float*)d_in[9];
  const float* out_w = (const float*)d_in[10];
  const float* out_b = (const float*)d_in[11];
  const float* ln_g  = (const float*)d_in[12];
  const float* ln_b  = (const float*)d_in[13];
  const float* l1_w  = (const float*)d_in[14];
  const float* l1_b  = (const float*)d_in[15];
  const float* l2_w  = (const float*)d_in[16];
  const float* l2_b  = (const float*)d_in[17];
  const float* pos_w = (const float*)d_in[18];
  const float* pos_b = (const float*)d_in[19];
  const float* num_w = (const float*)d_in[20];
  const float* num_b = (const float*)d_in[21];

  // ws layout (floats):
  // T2e 0 (12672) | w3r 12672 (147456) | owT 160128 (16384) |
  // l1T 176512 (16384) | l2T 192896 (16384) | digits 209280 (331776 int) |
  // x 541056 (42467328) | ctxg 43008384 (42467328)
  float* ws     = (float*)d_ws;
  float* T2e    = ws;
  float* w3r    = ws + 12672;
  float* owT    = ws + 160128;
  float* l1T    = ws + 176512;
  float* l2T    = ws + 192896;
  int*   digits = (int*)(ws + 209280);
  float* x      = ws + 541056;
  float* ctxg   = ws + 43008384;

  float* dout = (float*)d_out;
  float* asc  = dout + 2*NB;

  hipFuncSetAttribute((const void*)k_attn,
                      hipFuncAttributeMaxDynamicSharedMemorySize,
                      ATTN_LDS_BYTES);

  k_prep<<<dim3(818), dim3(256), 0, stream>>>(
      c1_w, c1_b, c2_w, c3_w, out_w, l1_w, l2_w,
      T2e, w3r, owT, l1T, l2T);
  k_stem<<<dim3(NB), dim3(256), 0, stream>>>(
      s, T2e, c2_b, w3r, c3_b, emb, x, digits);
  k_attn<<<dim3(NB), dim3(512), ATTN_LDS_BYTES, stream>>>(
      x, in_w, in_b, ctxg, asc);
  k_post<<<dim3(NB), dim3(256), 0, stream>>>(
      ctxg, owT, out_b, ln_g, ln_b, l1T, l1_b, l2T, l2_b,
      pos_w, pos_b, num_w, num_b, digits, dout);
}

// Round 6
// 4993.561 us; speedup vs baseline: 2.5278x; 1.0156x over previous
//
#include <hip/hip_runtime.h>
#include <stdint.h>
#include <math.h>

// ---------------------------------------------------------------------------
// p_net forward on MI355X.  B=4096 boards, N=81 cells, D=128, H=4 heads.
// Round 6: k_stem ic-chunked. conv2 (table) slice of 32 channels recomputed
// per pass into a [121][32] LDS chunk (15.5 KB vs 62 KB), conv3 accumulates
// across 4 passes in registers. Occupancy 2 -> ~4 blocks/CU; conv2 recompute
// cost is negligible (0.14 M adds vs 12 M FMA per board).
// Outputs (concat, float32): pos[4096], num[4096], asc[4096*81*81].
// ---------------------------------------------------------------------------

#define NB 4096

__device__ __forceinline__ float silu_f(float v) {
  return v / (1.0f + expf(-v));
}

__device__ __forceinline__ float4 zero4() { return make_float4(0.f,0.f,0.f,0.f); }

__device__ __forceinline__ void fma4b(float4& a, const float s, const float4 x) {
  a.x = fmaf(s, x.x, a.x); a.y = fmaf(s, x.y, a.y);
  a.z = fmaf(s, x.z, a.z); a.w = fmaf(s, x.w, a.w);
}

// sequential dot-accumulate: a += w·x, 4 fmaf, scalar accumulator
__device__ __forceinline__ void dacc(float& a, const float4 w, const float4 x) {
  a = fmaf(w.x, x.x, a); a = fmaf(w.y, x.y, a);
  a = fmaf(w.z, x.z, a); a = fmaf(w.w, x.w, a);
}

// ---------------- Threefry-2x32 (JAX partitionable) ------------------------
__device__ __forceinline__ void tf_round(uint32_t& x0, uint32_t& x1, int r) {
  x0 += x1;
  x1 = (x1 << r) | (x1 >> (32 - r));
  x1 ^= x0;
}

__device__ __forceinline__ void threefry2x32(uint32_t k0, uint32_t k1,
                                             uint32_t x0, uint32_t x1,
                                             uint32_t& o0, uint32_t& o1) {
  uint32_t k2 = k0 ^ k1 ^ 0x1BD11BDAu;
  x0 += k0; x1 += k1;
  tf_round(x0,x1,13); tf_round(x0,x1,15); tf_round(x0,x1,26); tf_round(x0,x1,6);
  x0 += k1; x1 += k2 + 1u;
  tf_round(x0,x1,17); tf_round(x0,x1,29); tf_round(x0,x1,16); tf_round(x0,x1,24);
  x0 += k2; x1 += k0 + 2u;
  tf_round(x0,x1,13); tf_round(x0,x1,15); tf_round(x0,x1,26); tf_round(x0,x1,6);
  x0 += k0; x1 += k1 + 3u;
  tf_round(x0,x1,17); tf_round(x0,x1,29); tf_round(x0,x1,16); tf_round(x0,x1,24);
  x0 += k1; x1 += k2 + 4u;
  tf_round(x0,x1,13); tf_round(x0,x1,15); tf_round(x0,x1,26); tf_round(x0,x1,6);
  x0 += k2; x1 += k0 + 5u;
  o0 = x0; o1 = x1;
}

__device__ __forceinline__ void jax_split42(uint32_t& k1a, uint32_t& k1b,
                                            uint32_t& k2a, uint32_t& k2b) {
  threefry2x32(0u, 42u, 0u, 0u, k1a, k1b);
  threefry2x32(0u, 42u, 0u, 1u, k2a, k2b);
}

__device__ __forceinline__ uint32_t jax_randbits(uint32_t ka, uint32_t kb,
                                                 uint32_t i) {
  uint32_t o0, o1;
  threefry2x32(ka, kb, 0u, i, o0, o1);
  return o0 ^ o1;
}

__device__ __forceinline__ float jax_gumbel_bits(uint32_t bits) {
  float f = __uint_as_float((bits >> 9) | 0x3f800000u) - 1.0f;
  const float tiny = 1.17549435e-38f;
  float u = fmaxf(tiny, f + tiny);
  return -logf(-logf(u));
}

// ---------------- prep: conv tables + weight transposes --------------------
__global__ __launch_bounds__(256) void k_prep(
    const float* __restrict__ c1_w, const float* __restrict__ c1_b,
    const float* __restrict__ c2_w, const float* __restrict__ c3_w,
    const float* __restrict__ out_w, const float* __restrict__ l1_w,
    const float* __restrict__ l2_w,
    float* __restrict__ T2e, float* __restrict__ w3r,
    float* __restrict__ owT, float* __restrict__ l1T, float* __restrict__ l2T)
{
  int idx = blockIdx.x * 256 + threadIdx.x;
  if (idx < 9*11*128) {
    int oc = idx & 127;
    int t  = idx >> 7;
    int g  = t % 11;
    int d  = t / 11;
    float acc = 0.f;
    if (g < 10) {
      int di = d / 3, dj = d % 3;
      for (int ic = 0; ic < 64; ++ic) {
        float x1 = c1_w[ic*10 + g] + c1_b[ic];
        acc += c2_w[((oc*64 + ic)*3 + di)*3 + dj] * x1;
      }
    }
    T2e[idx] = acc;
  } else if (idx < 160128) {
    int j  = idx - 12672;
    int ic = j & 127;
    int t  = j >> 7;
    int oc = t & 127;
    int d  = t >> 7;
    w3r[j] = c3_w[(oc*128 + ic)*9 + d];
  } else if (idx < 176512) {
    int j = idx - 160128;                      // j = k*128 + oc
    owT[j] = out_w[(j & 127)*128 + (j >> 7)];
  } else if (idx < 192896) {
    int j = idx - 176512;
    l1T[j] = l1_w[(j & 127)*128 + (j >> 7)];
  } else if (idx < 209280) {
    int j = idx - 192896;
    l2T[j] = l2_w[(j & 127)*128 + (j >> 7)];
  }
}

// ---------------- stem: digits -> conv2(table, ic-chunk) -> conv3 -> +emb --
// 256 threads/board. LDS: x2c[121][32] one ic-chunk of padded conv2 output.
// conv3 acc[11][4] in registers across the 4 ic-chunks.
__global__ __launch_bounds__(256) void k_stem(
    const float* __restrict__ s, const float* __restrict__ T2e,
    const float* __restrict__ c2_b, const float* __restrict__ w3r,
    const float* __restrict__ c3_b, const float* __restrict__ emb,
    float* __restrict__ xout, int* __restrict__ digits)
{
  __shared__ float x2c[121*32];   // 15.5 KB chunk
  __shared__ int   dg[121];       // padded digit grid, 10 = sentinel
  const int b   = blockIdx.x;
  const int tid = threadIdx.x;

  if (tid < 121) dg[tid] = 10;
  __syncthreads();

  if (tid < 81) {
    const float* sp = s + (size_t)b*810 + tid;
    float dv = 0.f;
    #pragma unroll
    for (int c = 1; c < 10; ++c) dv += (float)c * sp[c*81];
    int d = (int)(dv + 0.5f);
    dg[(tid/9 + 1)*11 + (tid%9 + 1)] = d;
    digits[b*81 + tid] = d;
  }

  const int oc4 = (tid & 31) * 4;   // conv3: 4 output channels
  const int cg  = tid >> 5;         // conv3: 8 groups of up to 11 cells
  const int ch4 = (tid & 7) * 4;    // conv2 chunk: 4 channels within 32
  const int pq  = tid >> 3;         // conv2 chunk: position group (0..31)

  int pb[11];
  #pragma unroll
  for (int ci = 0; ci < 11; ++ci) {
    int c  = cg*11 + ci;
    int rc = (c < 81) ? c : 0;
    pb[ci] = (rc/9)*11 + (rc%9);
  }

  float acc[11][4];
  #pragma unroll
  for (int ci = 0; ci < 11; ++ci) {
    acc[ci][0] = 0.f; acc[ci][1] = 0.f; acc[ci][2] = 0.f; acc[ci][3] = 0.f;
  }

  for (int icc = 0; icc < 4; ++icc) {
    __syncthreads();   // icc=0: dg ready; else: previous chunk's readers done

    // conv2 chunk: 32 channels [icc*32, icc*32+32) for all 121 padded cells
    {
      const float4 bias = *(const float4*)(c2_b + icc*32 + ch4);
      for (int p = pq; p < 121; p += 32) {
        const int pi = p / 11, pj = p - (p/11)*11;
        float4 a = zero4();
        if (pi >= 1 && pi <= 9 && pj >= 1 && pj <= 9) {
          a = bias;
          #pragma unroll
          for (int d = 0; d < 9; ++d) {
            const int g = dg[(pi - 1 + d/3)*11 + (pj - 1 + d%3)];
            const float4 t = *(const float4*)(T2e + (d*11 + g)*128 + icc*32 + ch4);
            a.x += t.x; a.y += t.y; a.z += t.z; a.w += t.w;
          }
          a.x = silu_f(a.x); a.y = silu_f(a.y);
          a.z = silu_f(a.z); a.w = silu_f(a.w);
        }
        *(float4*)(x2c + p*32 + ch4) = a;
      }
    }
    __syncthreads();

    // conv3 partial accumulation over this 32-channel chunk
    for (int d = 0; d < 9; ++d) {
      const int off = (d/3)*11 + (d%3);
      const float* wbase = w3r + (size_t)(d*128 + oc4)*128 + icc*32;
      #pragma unroll 2
      for (int k4 = 0; k4 < 8; ++k4) {
        const int k = k4*4;
        const float4 w0 = *(const float4*)(wbase + k);
        const float4 w1 = *(const float4*)(wbase + 128 + k);
        const float4 w2 = *(const float4*)(wbase + 256 + k);
        const float4 w3 = *(const float4*)(wbase + 384 + k);
        #pragma unroll
        for (int ci = 0; ci < 11; ++ci) {
          const float4 xv = *(const float4*)(x2c + (pb[ci] + off)*32 + k);
          dacc(acc[ci][0], w0, xv);
          dacc(acc[ci][1], w1, xv);
          dacc(acc[ci][2], w2, xv);
          dacc(acc[ci][3], w3, xv);
        }
      }
    }
  }

  // epilogue: bias + silu + emb -> xout[b][cell][128]
  {
    const float4 b3 = *(const float4*)(c3_b + oc4);
    #pragma unroll
    for (int ci = 0; ci < 11; ++ci) {
      int c = cg*11 + ci;
      if (c < 81) {
        const float4 e = *(const float4*)(emb + c*128 + oc4);
        float4 o;
        o.x = silu_f(acc[ci][0] + b3.x) + e.x;
        o.y = silu_f(acc[ci][1] + b3.y) + e.y;
        o.z = silu_f(acc[ci][2] + b3.z) + e.z;
        o.w = silu_f(acc[ci][3] + b3.w) + e.w;
        *(float4*)(xout + ((size_t)b*81 + c)*128 + oc4) = o;
      }
    }
  }
}

// ---------------- attention ------------------------------------------------
// 512 threads / board. Dynamic LDS layout (floats):
//  xL   @ 0      [81][132]  staged board activations (row-major, k-contig)
//  qkT  @ 10692  [84][68]   q,k cell-major: qkT[cell][m], m 0..31 q, 32..63 k
//  vL   @ 16404  [32][84]   v row-major: vL[j][cell]
//  sc   @ 19092  [81][84]   scores -> probs (pad cols zeroed)
//  red  @ 25896  [486]      softmax partials
//  rmax @ 26544  [81]
//  rinv @ 26625  [81]
#define ATTN_LDS_BYTES (27392*4)

__global__ __launch_bounds__(512) void k_attn(
    const float* __restrict__ x, const float* __restrict__ in_w,
    const float* __restrict__ in_b, float* __restrict__ ctxg,
    float* __restrict__ asc)
{
  extern __shared__ float sm[];
  float* xL   = sm;
  float* qkT  = sm + 10692;
  float* vL   = sm + 16404;
  float* sc   = sm + 19092;
  float* red  = sm + 25896;
  float* rmax = sm + 26544;
  float* rinv = sm + 26625;

  const int b   = blockIdx.x;
  const int tid = threadIdx.x;
  const int rg  = tid >> 5;     // 0..15
  const int cg  = tid & 31;     // 0..31

  // stage x -> xL (coalesced global float4)
  {
    const float4* xg = (const float4*)(x + (size_t)b*81*128);
    for (int i = tid; i < 81*32; i += 512) {
      int n = i >> 5, k4 = i & 31;
      *(float4*)(xL + n*132 + k4*4) = xg[n*32 + k4];
    }
  }

  float ascR[13];
  #pragma unroll
  for (int i = 0; i < 13; ++i) ascR[i] = 0.f;

  __syncthreads();

  for (int h = 0; h < 4; ++h) {
    // ---- QKV: rows m = rg*6+i (0..95), cells n = cg + {0,32,64}
    {
      float acc[18];
      #pragma unroll
      for (int i = 0; i < 18; ++i) acc[i] = 0.f;
      int rows[6];
      #pragma unroll
      for (int i = 0; i < 6; ++i) {
        int m = rg*6 + i;
        rows[i] = (m < 32) ? (h*32 + m)
                : (m < 64) ? (128 + h*32 + (m - 32))
                           : (256 + h*32 + (m - 64));
      }
      const float* x0p = xL + cg*132;
      const float* x1p = xL + (cg+32)*132;
      const float* x2p = xL + (cg+64)*132;
      #pragma unroll 2
      for (int k4 = 0; k4 < 32; ++k4) {
        const int ko = k4*4;
        float4 x0 = *(const float4*)(x0p + ko);
        float4 x1 = *(const float4*)(x1p + ko);
        float4 x2 = *(const float4*)(x2p + ko);
        #pragma unroll
        for (int i = 0; i < 6; ++i) {
          float4 w = *(const float4*)(in_w + rows[i]*128 + ko);
          dacc(acc[i*3 + 0], w, x0);
          dacc(acc[i*3 + 1], w, x1);
          dacc(acc[i*3 + 2], w, x2);
        }
      }
      #pragma unroll
      for (int i = 0; i < 6; ++i) {
        const int m = rg*6 + i;
        const float bias = in_b[rows[i]];
        float s0 = acc[i*3 + 0] + bias;
        float s1 = acc[i*3 + 1] + bias;
        float s2 = acc[i*3 + 2] + bias;
        if (m < 64) {
          qkT[cg*68 + m]      = s0;
          qkT[(cg+32)*68 + m] = s1;
          if (cg+64 < 81) qkT[(cg+64)*68 + m] = s2;
        } else {
          const int j = m - 64;
          vL[j*84 + cg]      = s0;
          vL[j*84 + cg+32]   = s1;
          if (cg+64 < 81)      vL[j*84 + cg+64] = s2;
          else if (cg+64 < 84) vL[j*84 + cg+64] = 0.f;   // zero pad cols
        }
      }
    }
    __syncthreads();

    // ---- scores: q = rg*6+i, k = cg*3+jj, dot over m=32
    {
      float acc[18];
      #pragma unroll
      for (int i = 0; i < 18; ++i) acc[i] = 0.f;
      const int q0 = rg*6, kc0 = cg*3;
      #pragma unroll 2
      for (int m4 = 0; m4 < 8; ++m4) {
        const int mo = m4*4;
        float4 kv0 = *(const float4*)(qkT + (kc0+0)*68 + 32 + mo);
        float4 kv1 = *(const float4*)(qkT + (kc0+1)*68 + 32 + mo);
        float4 kv2 = *(const float4*)(qkT + (kc0+2)*68 + 32 + mo);
        #pragma unroll
        for (int i = 0; i < 6; ++i) {
          float4 qv = *(const float4*)(qkT + (q0+i)*68 + mo);
          dacc(acc[i*3 + 0], qv, kv0);
          dacc(acc[i*3 + 1], qv, kv1);
          dacc(acc[i*3 + 2], qv, kv2);
        }
      }
      #pragma unroll
      for (int i = 0; i < 6; ++i) {
        const int q = q0 + i;
        if (q < 81) {
          const int qrow = q/9, qcol = q - qrow*9;
          const int qbox = (qrow/3)*3 + qcol/3;
          #pragma unroll
          for (int jj = 0; jj < 3; ++jj) {
            const int k = kc0 + jj;
            if (k < 81) {
              const int krow = k/9, kcol = k - krow*9;
              const int kbox = (krow/3)*3 + kcol/3;
              float msk = (h==0) ? (qrow==krow ? 1.f : 0.f)
                        : (h==1) ? (qcol==kcol ? 1.f : 0.f)
                        : (h==2) ? (qbox==kbox ? 1.f : 0.f)
                                 : 1.f;
              sc[q*84 + k] = acc[i*3 + jj] / 5.656854249492381f + msk;
            }
          }
        }
      }
    }
    __syncthreads();

    // ---- softmax: 6 threads per row
    if (tid < 486) {
      const int r = tid / 6, j = tid - (tid/6)*6;
      const int kb = j*14;
      float m = -INFINITY;
      for (int c = 0; c < 14; ++c) {
        int k = kb + c;
        if (k < 81) m = fmaxf(m, sc[r*84 + k]);
      }
      red[tid] = m;
    }
    __syncthreads();
    if (tid < 81) {
      float m = red[tid*6];
      #pragma unroll
      for (int j = 1; j < 6; ++j) m = fmaxf(m, red[tid*6 + j]);
      rmax[tid] = m;
    }
    __syncthreads();
    if (tid < 486) {
      const int r = tid / 6, j = tid - (tid/6)*6;
      const int kb = j*14;
      const float m = rmax[r];
      float ssum = 0.f;
      for (int c = 0; c < 14; ++c) {
        int k = kb + c;
        if (k < 81) ssum += expf(sc[r*84 + k] - m);
      }
      red[tid] = ssum;
    }
    __syncthreads();
    if (tid < 81) {
      float ssum = 0.f;
      #pragma unroll
      for (int j = 0; j < 6; ++j) ssum += red[tid*6 + j];
      rinv[tid] = 1.0f / ssum;
      sc[tid*84 + 81] = 0.f; sc[tid*84 + 82] = 0.f; sc[tid*84 + 83] = 0.f;
    }
    __syncthreads();

    // ---- probs in place + asc register accumulation
    #pragma unroll
    for (int i = 0; i < 13; ++i) {
      const int idx = tid + i*512;
      if (idx < 6561) {
        const int q = idx / 81, k = idx - q*81;
        float a = expf(sc[q*84 + k] - rmax[q]) * rinv[q];
        sc[q*84 + k] = a;
        ascR[i] += a;
      }
    }
    __syncthreads();

    // ---- ctx: n = (tid&31)*3+{0,1,2}, j = (tid>>5)*2+{0,1}; dot over k
    {
      const int ng = tid & 31, jg = tid >> 5;
      const int nb = ng*3, jb = jg*2;
      float a00=0.f, a01=0.f, a10=0.f, a11=0.f, a20=0.f, a21=0.f;
      const float* v0p = vL + jb*84;
      const float* v1p = vL + (jb+1)*84;
      const float* p0p = sc + nb*84;
      const float* p1p = sc + (nb+1)*84;
      const float* p2p = sc + (nb+2)*84;
      #pragma unroll 2
      for (int k4 = 0; k4 < 21; ++k4) {
        const int ko = k4*4;
        float4 v0 = *(const float4*)(v0p + ko);
        float4 v1 = *(const float4*)(v1p + ko);
        float4 p0 = *(const float4*)(p0p + ko);
        float4 p1 = *(const float4*)(p1p + ko);
        float4 p2 = *(const float4*)(p2p + ko);
        dacc(a00, p0, v0); dacc(a01, p0, v1);
        dacc(a10, p1, v0); dacc(a11, p1, v1);
        dacc(a20, p2, v0); dacc(a21, p2, v1);
      }
      float* cb = ctxg + ((size_t)b*128 + h*32)*81;
      if (nb   < 81) { cb[jb*81 + nb]       = a00;
                       cb[(jb+1)*81 + nb]   = a01; }
      if (nb+1 < 81) { cb[jb*81 + nb+1]     = a10;
                       cb[(jb+1)*81 + nb+1] = a11; }
      if (nb+2 < 81) { cb[jb*81 + nb+2]     = a20;
                       cb[(jb+1)*81 + nb+2] = a21; }
    }
    __syncthreads();
  } // heads

  // asc = mean over heads, single coalesced write
  #pragma unroll
  for (int i = 0; i < 13; ++i) {
    const int idx = tid + i*512;
    if (idx < 6561) asc[(size_t)b*6561 + idx] = 0.25f * ascR[i];
  }
}

// ---------------- post: out-proj, LN, l1, l2, heads + sampling -------------
__global__ __launch_bounds__(256) void k_post(
    const float* __restrict__ ctxg,
    const float* __restrict__ owT,  const float* __restrict__ out_b,
    const float* __restrict__ ln_g, const float* __restrict__ ln_b,
    const float* __restrict__ l1T,  const float* __restrict__ l1_b,
    const float* __restrict__ l2T,  const float* __restrict__ l2_b,
    const float* __restrict__ pos_w, const float* __restrict__ pos_b,
    const float* __restrict__ num_w, const float* __restrict__ num_b,
    const int* __restrict__ digits,  float* __restrict__ dout)
{
  __shared__ float yT[128*84];
  __shared__ float red[243];
  __shared__ float mu[81], rstd[81];
  __shared__ float vals[81];
  __shared__ int   posIdx;
  const int b   = blockIdx.x;
  const int tid = threadIdx.x;
  const int ocg = tid >> 3;   // 0..31
  const int ng  = tid & 7;    // 0..7 (ng==7 idle in GEMMs)

  // stage ctx (global [b][128][81]) -> yT[k][n]; zero pad cols 81..83
  {
    const float* cb = ctxg + (size_t)b*128*81;
    for (int i = tid; i < 128*81; i += 256) {
      int k = i / 81, n = i - k*81;
      yT[k*84 + n] = cb[i];
    }
    for (int i = tid; i < 128*3; i += 256) {
      int k = i / 3, c = i - k*3;
      yT[k*84 + 81 + c] = 0.f;
    }
  }
  __syncthreads();

  // ---- out projection (reads yT as ctx, writes yT as y) ----
  {
    float4 acc[4][3];
    #pragma unroll
    for (int c = 0; c < 4; ++c)
      { acc[c][0]=zero4(); acc[c][1]=zero4(); acc[c][2]=zero4(); }
    if (ng < 7) {
      #pragma unroll 2
      for (int k = 0; k < 128; ++k) {
        const float4 wv = *(const float4*)(owT + k*128 + ocg*4);
        const float* yr = yT + k*84 + ng*12;
        float4 x0 = *(const float4*)(yr);
        float4 x1 = *(const float4*)(yr + 4);
        float4 x2 = *(const float4*)(yr + 8);
        fma4b(acc[0][0], wv.x, x0); fma4b(acc[0][1], wv.x, x1); fma4b(acc[0][2], wv.x, x2);
        fma4b(acc[1][0], wv.y, x0); fma4b(acc[1][1], wv.y, x1); fma4b(acc[1][2], wv.y, x2);
        fma4b(acc[2][0], wv.z, x0); fma4b(acc[2][1], wv.z, x1); fma4b(acc[2][2], wv.z, x2);
        fma4b(acc[3][0], wv.w, x0); fma4b(acc[3][1], wv.w, x1); fma4b(acc[3][2], wv.w, x2);
      }
    }
    __syncthreads();
    if (ng < 7) {
      #pragma unroll
      for (int c = 0; c < 4; ++c) {
        const float bv = out_b[ocg*4 + c];
        #pragma unroll
        for (int t = 0; t < 3; ++t) {
          float4 o = acc[c][t];
          o.x += bv; o.y += bv; o.z += bv; o.w += bv;
          *(float4*)(yT + (ocg*4 + c)*84 + ng*12 + t*4) = o;
        }
      }
    }
  }
  __syncthreads();

  // ---- LayerNorm over k (columns n) ----
  if (tid < 243) {
    const int n = tid/3, j = tid - (tid/3)*3;
    float ssum = 0.f;
    for (int c = 0; c < 43; ++c) {
      int k = j*43 + c;
      if (k < 128) ssum += yT[k*84 + n];
    }
    red[tid] = ssum;
  }
  __syncthreads();
  if (tid < 81)
    mu[tid] = (red[tid*3] + red[tid*3+1] + red[tid*3+2]) * (1.0f/128.0f);
  __syncthreads();
  if (tid < 243) {
    const int n = tid/3, j = tid - (tid/3)*3;
    const float m = mu[n];
    float ssum = 0.f;
    for (int c = 0; c < 43; ++c) {
      int k = j*43 + c;
      if (k < 128) { float d = yT[k*84 + n] - m; ssum += d*d; }
    }
    red[tid] = ssum;
  }
  __syncthreads();
  if (tid < 81) {
    float v = (red[tid*3] + red[tid*3+1] + red[tid*3+2]) * (1.0f/128.0f);
    rstd[tid] = 1.0f / sqrtf(v + 1e-5f);
  }
  __syncthreads();
  for (int i = tid; i < 128*81; i += 256) {
    const int k = i / 81, n = i - k*81;
    yT[k*84 + n] = (yT[k*84 + n] - mu[n]) * rstd[n] * ln_g[k] + ln_b[k];
  }
  __syncthreads();

  // ---- l1 (silu) ----
  {
    float4 acc[4][3];
    #pragma unroll
    for (int c = 0; c < 4; ++c)
      { acc[c][0]=zero4(); acc[c][1]=zero4(); acc[c][2]=zero4(); }
    if (ng < 7) {
      #pragma unroll 2
      for (int k = 0; k < 128; ++k) {
        const float4 wv = *(const float4*)(l1T + k*128 + ocg*4);
        const float* yr = yT + k*84 + ng*12;
        float4 x0 = *(const float4*)(yr);
        float4 x1 = *(const float4*)(yr + 4);
        float4 x2 = *(const float4*)(yr + 8);
        fma4b(acc[0][0], wv.x, x0); fma4b(acc[0][1], wv.x, x1); fma4b(acc[0][2], wv.x, x2);
        fma4b(acc[1][0], wv.y, x0); fma4b(acc[1][1], wv.y, x1); fma4b(acc[1][2], wv.y, x2);
        fma4b(acc[2][0], wv.z, x0); fma4b(acc[2][1], wv.z, x1); fma4b(acc[2][2], wv.z, x2);
        fma4b(acc[3][0], wv.w, x0); fma4b(acc[3][1], wv.w, x1); fma4b(acc[3][2], wv.w, x2);
      }
    }
    __syncthreads();
    if (ng < 7) {
      #pragma unroll
      for (int c = 0; c < 4; ++c) {
        const float bv = l1_b[ocg*4 + c];
        #pragma unroll
        for (int t = 0; t < 3; ++t) {
          float4 o = acc[c][t];
          o.x = silu_f(o.x + bv); o.y = silu_f(o.y + bv);
          o.z = silu_f(o.z + bv); o.w = silu_f(o.w + bv);
          *(float4*)(yT + (ocg*4 + c)*84 + ng*12 + t*4) = o;
        }
      }
    }
  }
  __syncthreads();

  // ---- l2 (silu) ----
  {
    float4 acc[4][3];
    #pragma unroll
    for (int c = 0; c < 4; ++c)
      { acc[c][0]=zero4(); acc[c][1]=zero4(); acc[c][2]=zero4(); }
    if (ng < 7) {
      #pragma unroll 2
      for (int k = 0; k < 128; ++k) {
        const float4 wv = *(const float4*)(l2T + k*128 + ocg*4);
        const float* yr = yT + k*84 + ng*12;
        float4 x0 = *(const float4*)(yr);
        float4 x1 = *(const float4*)(yr + 4);
        float4 x2 = *(const float4*)(yr + 8);
        fma4b(acc[0][0], wv.x, x0); fma4b(acc[0][1], wv.x, x1); fma4b(acc[0][2], wv.x, x2);
        fma4b(acc[1][0], wv.y, x0); fma4b(acc[1][1], wv.y, x1); fma4b(acc[1][2], wv.y, x2);
        fma4b(acc[2][0], wv.z, x0); fma4b(acc[2][1], wv.z, x1); fma4b(acc[2][2], wv.z, x2);
        fma4b(acc[3][0], wv.w, x0); fma4b(acc[3][1], wv.w, x1); fma4b(acc[3][2], wv.w, x2);
      }
    }
    __syncthreads();
    if (ng < 7) {
      #pragma unroll
      for (int c = 0; c < 4; ++c) {
        const float bv = l2_b[ocg*4 + c];
        #pragma unroll
        for (int t = 0; t < 3; ++t) {
          float4 o = acc[c][t];
          o.x = silu_f(o.x + bv); o.y = silu_f(o.y + bv);
          o.z = silu_f(o.z + bv); o.w = silu_f(o.w + bv);
          *(float4*)(yT + (ocg*4 + c)*84 + ng*12 + t*4) = o;
        }
      }
    }
  }
  __syncthreads();

  // ---- position head + gumbel sampling ----
  uint32_t k1a, k1b, k2a, k2b;
  jax_split42(k1a, k1b, k2a, k2b);

  if (tid < 243) {
    const int n = tid/3, j = tid - (tid/3)*3;
    float ssum = 0.f;
    for (int c = 0; c < 43; ++c) {
      int k = j*43 + c;
      if (k < 128) ssum += yT[k*84 + n] * pos_w[k];
    }
    red[tid] = ssum;
  }
  __syncthreads();
  if (tid < 81) {
    float acc = red[tid*3] + red[tid*3+1] + red[tid*3+2] + pos_b[0];
    if (digits[b*81 + tid] != 0) acc = -1e9f;
    uint32_t bits = jax_randbits(k1a, k1b, (uint32_t)(b*81 + tid));
    vals[tid] = acc + jax_gumbel_bits(bits);
  }
  __syncthreads();
  if (tid == 0) {
    float best = vals[0]; int bi = 0;
    for (int n = 1; n < 81; ++n)
      if (vals[n] > best) { best = vals[n]; bi = n; }
    posIdx = bi;
    dout[b] = (float)bi;
  }
  __syncthreads();
  const int pos = posIdx;

  // ---- number head at sampled position ----
  if (tid < 80) {
    const int d = tid >> 3, j = tid & 7;
    float ssum = 0.f;
    #pragma unroll
    for (int c = 0; c < 16; ++c) {
      int k = j*16 + c;
      ssum += yT[k*84 + pos] * num_w[d*128 + k];
    }
    red[tid] = ssum;
  }
  __syncthreads();
  if (tid < 10) {
    float acc = num_b[tid];
    #pragma unroll
    for (int j = 0; j < 8; ++j) acc += red[tid*8 + j];
    if (tid == 0) acc = -INFINITY;
    uint32_t bits = jax_randbits(k2a, k2b, (uint32_t)(b*10 + tid));
    vals[tid] = acc + jax_gumbel_bits(bits);
  }
  __syncthreads();
  if (tid == 0) {
    float best = vals[0]; int bi = 0;
    for (int d = 1; d < 10; ++d)
      if (vals[d] > best) { best = vals[d]; bi = d; }
    dout[NB + b] = (float)bi;
  }
}

// ---------------------------------------------------------------------------
extern "C" void kernel_launch(void* const* d_in, const int* in_sizes, int n_in,
                              void* d_out, int out_size, void* d_ws, size_t ws_size,
                              hipStream_t stream) {
  const float* s     = (const float*)d_in[0];
  const float* c1_w  = (const float*)d_in[1];
  const float* c1_b  = (const float*)d_in[2];
  const float* c2_w  = (const float*)d_in[3];
  const float* c2_b  = (const float*)d_in[4];
  const float* c3_w  = (const float*)d_in[5];
  const float* c3_b  = (const float*)d_in[6];
  const float* emb   = (const float*)d_in[7];
  const float* in_w  = (const float*)d_in[8];
  const float* in_b  = (const float*)d_in[9];
  const float* out_w = (const float*)d_in[10];
  const float* out_b = (const float*)d_in[11];
  const float* ln_g  = (const float*)d_in[12];
  const float* ln_b  = (const float*)d_in[13];
  const float* l1_w  = (const float*)d_in[14];
  const float* l1_b  = (const float*)d_in[15];
  const float* l2_w  = (const float*)d_in[16];
  const float* l2_b  = (const float*)d_in[17];
  const float* pos_w = (const float*)d_in[18];
  const float* pos_b = (const float*)d_in[19];
  const float* num_w = (const float*)d_in[20];
  const float* num_b = (const float*)d_in[21];

  // ws layout (floats):
  // T2e 0 (12672) | w3r 12672 (147456) | owT 160128 (16384) |
  // l1T 176512 (16384) | l2T 192896 (16384) | digits 209280 (331776 int) |
  // x 541056 (42467328) | ctxg 43008384 (42467328)
  float* ws     = (float*)d_ws;
  float* T2e    = ws;
  float* w3r    = ws + 12672;
  float* owT    = ws + 160128;
  float* l1T    = ws + 176512;
  float* l2T    = ws + 192896;
  int*   digits = (int*)(ws + 209280);
  float* x      = ws + 541056;
  float* ctxg   = ws + 43008384;

  float* dout = (float*)d_out;
  float* asc  = dout + 2*NB;

  hipFuncSetAttribute((const void*)k_attn,
                      hipFuncAttributeMaxDynamicSharedMemorySize,
                      ATTN_LDS_BYTES);

  k_prep<<<dim3(818), dim3(256), 0, stream>>>(
      c1_w, c1_b, c2_w, c3_w, out_w, l1_w, l2_w,
      T2e, w3r, owT, l1T, l2T);
  k_stem<<<dim3(NB), dim3(256), 0, stream>>>(
      s, T2e, c2_b, w3r, c3_b, emb, x, digits);
  k_attn<<<dim3(NB), dim3(512), ATTN_LDS_BYTES, stream>>>(
      x, in_w, in_b, ctxg, asc);
  k_post<<<dim3(NB), dim3(256), 0, stream>>>(
      ctxg, owT, out_b, ln_g, ln_b, l1T, l1_b, l2T, l2_b,
      pos_w, pos_b, num_w, num_b, digits, dout);
}